// Round 5
// baseline (177.317 us; speedup 1.0000x reference)
//
#include <hip/hip_runtime.h>
#include <hip/hip_bf16.h>
#include <stdint.h>

constexpr int B_ = 2, L_ = 2048, DM = 768, NH_ = 12, F_ = 16, DH_ = 64;
constexpr int NPROJ = 1152;
constexpr int CH = 64, NCH = L_ / CH;  // scan chunking

typedef __bf16 bf16x8 __attribute__((ext_vector_type(8)));
typedef __bf16 bf16x4 __attribute__((ext_vector_type(4)));
typedef float f32x4 __attribute__((ext_vector_type(4)));
typedef float f32x16 __attribute__((ext_vector_type(16)));

#define GLOAD16(g, l)                                                        \
  __builtin_amdgcn_global_load_lds(                                          \
      (const __attribute__((address_space(1))) void*)(g),                    \
      (__attribute__((address_space(3))) void*)(l), 16, 0, 0)

// ---------------- cast + weight transpose --------------------------------
__global__ __launch_bounds__(256)
void prep_cast(const float* __restrict__ hs, const float* __restrict__ Wq,
               const float* __restrict__ Wk, const float* __restrict__ Wv,
               const float* __restrict__ Wo, __bf16* __restrict__ hsb,
               __bf16* __restrict__ WqkvT, __bf16* __restrict__ WoT) {
  int idx = blockIdx.x * 256 + threadIdx.x;
  int stride = gridDim.x * 256;
  for (int i = idx; i < B_ * L_ * DM; i += stride) hsb[i] = (__bf16)hs[i];
  for (int i = idx; i < NPROJ * DM; i += stride) {
    int n = i / DM, k = i % DM;
    float v;
    if (n < 192)      v = Wq[(size_t)k * 192 + n];
    else if (n < 384) v = Wk[(size_t)k * 192 + (n - 192)];
    else              v = Wv[(size_t)k * 768 + (n - 384)];
    WqkvT[i] = (__bf16)v;
  }
  for (int i = idx; i < DM * DM; i += stride) {
    int n = i / DM, k = i % DM;
    WoT[i] = (__bf16)Wo[(size_t)k * DM + n];
  }
}

// ---------------- bf16 MFMA GEMM: C(MxN) = A(MxK) @ Bt(NxK)^T ------------
__global__ __launch_bounds__(256)
void gemm_bf16(const __bf16* __restrict__ A, const __bf16* __restrict__ Bt,
               int M, int N, int K, float* __restrict__ C,
               __bf16* __restrict__ Qh, int mode) {
  __shared__ __align__(16) __bf16 Al[128 * 32];
  __shared__ __align__(16) __bf16 Bl[128 * 32];
  int tid = threadIdx.x;
  int m0 = blockIdx.y * 128, n0 = blockIdx.x * 128;
  int w = tid >> 6, l = tid & 63, lr = l & 15, lg = l >> 4;
  int wr = w >> 1, wc = w & 1;
  f32x4 acc[4][4] = {};
  const __bf16* Ab = A + (size_t)m0 * K;
  const __bf16* Bb = Bt + (size_t)n0 * K;
  for (int k0 = 0; k0 < K; k0 += 32) {
    __syncthreads();
#pragma unroll
    for (int i = 0; i < 2; i++) {
      int idx = i * 256 + tid;
      int row = idx >> 2, ch = idx & 3;
      GLOAD16(Ab + (size_t)row * K + k0 + ch * 8, &Al[idx * 8]);
    }
#pragma unroll
    for (int i = 0; i < 2; i++) {
      int idx = i * 256 + tid;
      int row = idx >> 2, ch = idx & 3;
      GLOAD16(Bb + (size_t)row * K + k0 + ch * 8, &Bl[idx * 8]);
    }
    asm volatile("s_waitcnt vmcnt(0)" ::: "memory");
    __syncthreads();
    bf16x8 af[4], bfr[4];
#pragma unroll
    for (int mi = 0; mi < 4; mi++)
      af[mi] = *(const bf16x8*)&Al[(wr * 64 + mi * 16 + lr) * 32 + lg * 8];
#pragma unroll
    for (int ni = 0; ni < 4; ni++)
      bfr[ni] = *(const bf16x8*)&Bl[(wc * 64 + ni * 16 + lr) * 32 + lg * 8];
#pragma unroll
    for (int mi = 0; mi < 4; mi++)
#pragma unroll
      for (int ni = 0; ni < 4; ni++)
        acc[mi][ni] = __builtin_amdgcn_mfma_f32_16x16x32_bf16(
            af[mi], bfr[ni], acc[mi][ni], 0, 0, 0);
  }
#pragma unroll
  for (int mi = 0; mi < 4; mi++)
#pragma unroll
    for (int ni = 0; ni < 4; ni++) {
      int n = n0 + wc * 64 + ni * 16 + lr;
#pragma unroll
      for (int r = 0; r < 4; r++) {
        int m = m0 + wr * 64 + mi * 16 + lg * 4 + r;
        float v = acc[mi][ni][r];
        if (mode == 1 && n < 192) {
          int h = n >> 4, f = n & 15;
          int b = m >> 11, ll = m & 2047;
          Qh[((size_t)(b * NH_ + h) * L_ + ll) * F_ + f] = (__bf16)v;
        } else {
          C[(size_t)m * N + n] = v;
        }
      }
    }
}

// ---------------- chunked column sums: csum[bh][ch][80] ------------------
__global__ __launch_bounds__(128)
void scan_sum(const float* __restrict__ proj, float* __restrict__ csum) {
  int bh = blockIdx.y, ch = blockIdx.x;
  int b = bh / NH_, h = bh % NH_;
  int c = threadIdx.x;
  if (c >= 80) return;
  int off = (c < 16) ? (192 + h * 16 + c) : (384 + h * 64 + (c - 16));
  const float* src = proj + ((size_t)b * L_ + ch * CH) * NPROJ + off;
  float s = 0.f;
#pragma unroll 8
  for (int r = 0; r < CH; r++) s += src[(size_t)r * NPROJ];
  csum[((size_t)bh * NCH + ch) * 80 + c] = s;
}

// ---------------- apply: prefix base + in-chunk mean scan ----------------
__global__ __launch_bounds__(128)
void scan_apply(const float* __restrict__ proj, const float* __restrict__ csum,
                __bf16* __restrict__ CKh, __bf16* __restrict__ CVT,
                __bf16* __restrict__ Yb) {
  int bh = blockIdx.y, ch = blockIdx.x;
  int b = bh / NH_, h = bh % NH_;
  int c = threadIdx.x;
  if (c >= 80) return;
  int off = (c < 16) ? (192 + h * 16 + c) : (384 + h * 64 + (c - 16));
  const float* src = proj + ((size_t)b * L_ + ch * CH) * NPROJ + off;
  float run = 0.f;
  for (int j = 0; j < ch; j++) run += csum[((size_t)bh * NCH + j) * 80 + c];
  if (c < 16) {
    __bf16* ckp = CKh + ((size_t)bh * L_ + ch * CH) * F_ + c;
    for (int r = 0; r < CH; r++) {
      float val = src[(size_t)r * NPROJ];
      run += val;
      float mean = run / (float)(ch * CH + r + 1);
      ckp[(size_t)r * F_] = (__bf16)(val - mean);
    }
  } else {
    int d = c - 16;
    __bf16* cvp = CVT + ((size_t)bh * DH_ + d) * L_ + ch * CH;
    __bf16* yp = Yb + ((size_t)(b * L_ + ch * CH)) * DM + h * DH_ + d;
    for (int r = 0; r < CH; r++) {
      float val = src[(size_t)r * NPROJ];
      run += val;
      float mean = run / (float)(ch * CH + r + 1);
      cvp[r] = (__bf16)(val - mean);
      yp[(size_t)r * DM] = (__bf16)mean;
    }
  }
}

// ---------------- attention core on 32x32x16 MFMA ------------------------
// block = (bh, qtile of 128), 4 waves; wave w owns q rows [w*32, w*32+32).
// Q / CK fragments read straight from global (row-major [*][16], 16B/lane).
// LDS: CVl (64x128, swizzled) + Pl (128x128, swizzled, wave-private rows).
__global__ __launch_bounds__(256)
void attn_mfma(const __bf16* __restrict__ Qh, const __bf16* __restrict__ CKh,
               const __bf16* __restrict__ CVT, __bf16* __restrict__ qkv,
               float* __restrict__ rs2) {
  __shared__ __align__(16) __bf16 CVl[64 * 128];   // 16 KB, swizzled
  __shared__ __align__(16) __bf16 Pl[128 * 128];   // 32 KB, swizzled
  int bh = blockIdx.y;
  int qt = (gridDim.x - 1) - blockIdx.x;  // big tiles scheduled first
  int q0 = qt * 128;
  int tid = threadIdx.x;
  int w = tid >> 6, l = tid & 63;
  int lp = l & 31, hi = l >> 5;

  // A-fragment of Q: row = q0 + w*32 + lp, k(=f) = hi*8 + j
  bf16x8 qa = *(const bf16x8*)(Qh + ((size_t)bh * L_ + q0 + w * 32 + lp) * F_ + hi * 8);

  f32x16 pv0 = {}, pv1 = {};
  float s2[16] = {};
  char* PlB = (char*)Pl;
  char* CVlB = (char*)CVl;

  for (int pt = 0; pt <= qt; pt++) {
    int p0 = pt * 128;
    __syncthreads();
#pragma unroll
    for (int it = 0; it < 4; it++) {  // stage CV^T tile (64 d x 128 kv)
      int idx = it * 256 + tid;
      int dd = idx >> 4, seg = idx & 15;
      bf16x8 v = *(const bf16x8*)(CVT + ((size_t)bh * DH_ + dd) * L_ + p0 + seg * 8);
      *(bf16x8*)(CVlB + dd * 256 + ((seg * 16) ^ ((dd & 15) << 4))) = v;
    }
    __syncthreads();

    bool diag = (pt == qt);
#pragma unroll
    for (int pt4 = 0; pt4 < 4; pt4++) {
      // B-fragment of CK^T: col(=p) = p0+pt4*32+lp, k(=f) = hi*8+j
      bf16x8 bk = *(const bf16x8*)(CKh + ((size_t)bh * L_ + p0 + pt4 * 32 + lp) * F_ + hi * 8);
      f32x16 s = {};
      s = __builtin_amdgcn_mfma_f32_32x32x16_bf16(qa, bk, s, 0, 0, 0);
      int pl = pt4 * 32 + lp;
#pragma unroll
      for (int reg = 0; reg < 16; reg++) {
        int ql = (reg & 3) + 8 * (reg >> 2) + 4 * hi;  // 0..31
        float sv = s[reg];
        if (diag && pl > w * 32 + ql) sv = 0.f;
        s2[reg] = fmaf(sv, sv, s2[reg]);
        int qr = w * 32 + ql;
        *(__bf16*)(PlB + qr * 256 + ((pl * 2) ^ ((ql & 15) << 4))) = (__bf16)sv;
      }
    }

    // PV: out(32q x 64d per wave) += P(32x128) @ CV(128x64)
#pragma unroll
    for (int kt = 0; kt < 8; kt++) {
      int colsw = (kt * 32 + hi * 16) ^ ((lp & 15) << 4);
      bf16x8 pa = *(const bf16x8*)(PlB + (w * 32 + lp) * 256 + colsw);
      bf16x8 bv0 = *(const bf16x8*)(CVlB + lp * 256 + colsw);
      bf16x8 bv1 = *(const bf16x8*)(CVlB + (32 + lp) * 256 + colsw);
      pv0 = __builtin_amdgcn_mfma_f32_32x32x16_bf16(pa, bv0, pv0, 0, 0, 0);
      pv1 = __builtin_amdgcn_mfma_f32_32x32x16_bf16(pa, bv1, pv1, 0, 0, 0);
    }
  }

  // reduce s^2 over the 32 lanes sharing hi (each holds one p-slice)
#pragma unroll
  for (int reg = 0; reg < 16; reg++) {
    float v = s2[reg];
    v += __shfl_xor(v, 1, 64);
    v += __shfl_xor(v, 2, 64);
    v += __shfl_xor(v, 4, 64);
    v += __shfl_xor(v, 8, 64);
    v += __shfl_xor(v, 16, 64);
    s2[reg] = v;
  }
  if (lp == 0) {
#pragma unroll
    for (int reg = 0; reg < 16; reg++) {
      int q = q0 + w * 32 + (reg & 3) + 8 * (reg >> 2) + 4 * hi;
      rs2[(size_t)bh * L_ + q] = s2[reg] * (1.0f / 128.0f);
    }
  }
#pragma unroll
  for (int reg = 0; reg < 16; reg++) {
    int q = q0 + w * 32 + (reg & 3) + 8 * (reg >> 2) + 4 * hi;
    __bf16* qp = qkv + ((size_t)bh * L_ + q) * DH_ + lp;
    qp[0]  = (__bf16)(pv0[reg] * 0.125f);
    qp[32] = (__bf16)(pv1[reg] * 0.125f);
  }
}

// ---------------- denominator scan ---------------------------------------
__global__ __launch_bounds__(256)
void denom_kernel(const float* __restrict__ rs2, float* __restrict__ denom) {
  int bh = blockIdx.x;
  int t = threadIdx.x;
  const float* rs = rs2 + (size_t)bh * L_;
  float vals[8];
  float run = 0.f;
#pragma unroll
  for (int i = 0; i < 8; i++) { run += rs[t * 8 + i]; vals[i] = run; }
  __shared__ float part[256];
  part[t] = run;
  __syncthreads();
  for (int o = 1; o < 256; o <<= 1) {
    float add = (t >= o) ? part[t - o] : 0.f;
    __syncthreads();
    part[t] += add;
    __syncthreads();
  }
  float base = (t > 0) ? part[t - 1] : 0.f;
#pragma unroll
  for (int i = 0; i < 8; i++) {
    int ll = t * 8 + i;
    denom[(size_t)bh * L_ + ll] = (float)(ll + 1) + base + vals[i];
  }
}

// ---------------- combine: Yb += qkv/denom (in place, bf16) --------------
__global__ __launch_bounds__(256)
void combine_kernel(const __bf16* __restrict__ qkv, const float* __restrict__ denom,
                    __bf16* __restrict__ Yb) {
  int bh = blockIdx.y, lt = blockIdx.x;
  int b = bh / NH_, h = bh % NH_;
  int t = threadIdx.x;
  int l0 = lt * 256;
  __shared__ float dinv[256];
  dinv[t] = 1.0f / denom[(size_t)bh * L_ + l0 + t];
  __syncthreads();
#pragma unroll
  for (int it = 0; it < 8; it++) {
    int v = it * 256 + t;
    int ll = v >> 3, d8 = v & 7;
    bf16x8 q8 = *(const bf16x8*)(qkv + ((size_t)bh * L_ + l0 + ll) * DH_ + d8 * 8);
    __bf16* yp = Yb + ((size_t)(b * L_ + l0 + ll)) * DM + h * DH_ + d8 * 8;
    bf16x8 y8 = *(const bf16x8*)yp;
    float iv = dinv[ll];
#pragma unroll
    for (int j = 0; j < 8; j++)
      y8[j] = (__bf16)((float)y8[j] + (float)q8[j] * iv);
    *(bf16x8*)yp = y8;
  }
}

extern "C" void kernel_launch(void* const* d_in, const int* in_sizes, int n_in,
                              void* d_out, int out_size, void* d_ws, size_t ws_size,
                              hipStream_t stream) {
  const float* hs = (const float*)d_in[0];
  const float* Wq = (const float*)d_in[1];
  const float* Wk = (const float*)d_in[2];
  const float* Wv = (const float*)d_in[3];
  const float* Wo = (const float*)d_in[4];
  float* out = (float*)d_out;
  char* w = (char*)d_ws;

  __bf16* hsb   = (__bf16*)(w);                      // 6,291,456
  __bf16* WqkvT = (__bf16*)(w + 6291456);            // 1,769,472
  __bf16* WoT   = (__bf16*)(w + 8060928);            // 1,179,648
  float*  proj  = (float*)(w + 9240576);             // 18,874,368
  __bf16* qkvb  = (__bf16*)(w + 28114944);           // 6,291,456
  __bf16* Qh    = (__bf16*)(w + 34406400);           // 1,572,864
  __bf16* CKh   = (__bf16*)(w + 35979264);           // 1,572,864
  __bf16* CVTg  = (__bf16*)(w + 37552128);           // 6,291,456
  __bf16* Yb    = (__bf16*)(w + 43843584);           // 6,291,456
  float*  rs2   = (float*)(w + 50135040);            // 98,304
  float*  denom = (float*)(w + 50233344);            // 98,304
  float*  csum  = (float*)(w + 50331648);            // 245,760

  prep_cast<<<1024, 256, 0, stream>>>(hs, Wq, Wk, Wv, Wo, hsb, WqkvT, WoT);
  dim3 g1(NPROJ / 128, (B_ * L_) / 128);
  gemm_bf16<<<g1, 256, 0, stream>>>(hsb, WqkvT, B_ * L_, NPROJ, DM, proj, Qh, 1);
  dim3 gs(NCH, B_ * NH_);
  scan_sum<<<gs, 128, 0, stream>>>(proj, csum);
  scan_apply<<<gs, 128, 0, stream>>>(proj, csum, CKh, CVTg, Yb);
  dim3 g3(L_ / 128, 24);
  attn_mfma<<<g3, 256, 0, stream>>>(Qh, CKh, CVTg, qkvb, rs2);
  denom_kernel<<<24, 256, 0, stream>>>(rs2, denom);
  dim3 g5(8, 24);
  combine_kernel<<<g5, 256, 0, stream>>>(qkvb, denom, Yb);
  dim3 g6(DM / 128, (B_ * L_) / 128);
  gemm_bf16<<<g6, 256, 0, stream>>>(Yb, WoT, B_ * L_, DM, DM, out, nullptr, 0);
}

// Round 6
// 158.075 us; speedup vs baseline: 1.1217x; 1.1217x over previous
//
#include <hip/hip_runtime.h>
#include <hip/hip_bf16.h>
#include <stdint.h>

constexpr int B_ = 2, L_ = 2048, DM = 768, NH_ = 12, F_ = 16, DH_ = 64;
constexpr int NPROJ = 1152;
constexpr int CH = 64, NCH = L_ / CH;  // scan chunking

typedef __bf16 bf16x8 __attribute__((ext_vector_type(8)));
typedef __bf16 bf16x4 __attribute__((ext_vector_type(4)));
typedef float f32x4 __attribute__((ext_vector_type(4)));
typedef float f32x16 __attribute__((ext_vector_type(16)));
typedef unsigned u32x2 __attribute__((ext_vector_type(2)));

#define GLOAD16(g, l)                                                        \
  __builtin_amdgcn_global_load_lds(                                          \
      (const __attribute__((address_space(1))) void*)(g),                    \
      (__attribute__((address_space(3))) void*)(l), 16, 0, 0)

__device__ __forceinline__ unsigned cvt_pk_bf16(float lo, float hi) {
  unsigned r;
  asm("v_cvt_pk_bf16_f32 %0, %1, %2" : "=v"(r) : "v"(lo), "v"(hi));
  return r;
}

// ---------------- cast + weight transpose --------------------------------
__global__ __launch_bounds__(256)
void prep_cast(const float* __restrict__ hs, const float* __restrict__ Wq,
               const float* __restrict__ Wk, const float* __restrict__ Wv,
               const float* __restrict__ Wo, __bf16* __restrict__ hsb,
               __bf16* __restrict__ WqkvT, __bf16* __restrict__ WoT) {
  int idx = blockIdx.x * 256 + threadIdx.x;
  int stride = gridDim.x * 256;
  for (int i = idx; i < B_ * L_ * DM; i += stride) hsb[i] = (__bf16)hs[i];
  for (int i = idx; i < NPROJ * DM; i += stride) {
    int n = i / DM, k = i % DM;
    float v;
    if (n < 192)      v = Wq[(size_t)k * 192 + n];
    else if (n < 384) v = Wk[(size_t)k * 192 + (n - 192)];
    else              v = Wv[(size_t)k * 768 + (n - 384)];
    WqkvT[i] = (__bf16)v;
  }
  for (int i = idx; i < DM * DM; i += stride) {
    int n = i / DM, k = i % DM;
    WoT[i] = (__bf16)Wo[(size_t)k * DM + n];
  }
}

// ---------------- bf16 MFMA GEMM: C(MxN) = A(MxK) @ Bt(NxK)^T ------------
__global__ __launch_bounds__(256)
void gemm_bf16(const __bf16* __restrict__ A, const __bf16* __restrict__ Bt,
               int M, int N, int K, float* __restrict__ C,
               __bf16* __restrict__ Qh, int mode) {
  __shared__ __align__(16) __bf16 Al[128 * 32];
  __shared__ __align__(16) __bf16 Bl[128 * 32];
  int tid = threadIdx.x;
  int m0 = blockIdx.y * 128, n0 = blockIdx.x * 128;
  int w = tid >> 6, l = tid & 63, lr = l & 15, lg = l >> 4;
  int wr = w >> 1, wc = w & 1;
  f32x4 acc[4][4] = {};
  const __bf16* Ab = A + (size_t)m0 * K;
  const __bf16* Bb = Bt + (size_t)n0 * K;
  for (int k0 = 0; k0 < K; k0 += 32) {
    __syncthreads();
#pragma unroll
    for (int i = 0; i < 2; i++) {
      int idx = i * 256 + tid;
      int row = idx >> 2, ch = idx & 3;
      GLOAD16(Ab + (size_t)row * K + k0 + ch * 8, &Al[idx * 8]);
    }
#pragma unroll
    for (int i = 0; i < 2; i++) {
      int idx = i * 256 + tid;
      int row = idx >> 2, ch = idx & 3;
      GLOAD16(Bb + (size_t)row * K + k0 + ch * 8, &Bl[idx * 8]);
    }
    asm volatile("s_waitcnt vmcnt(0)" ::: "memory");
    __syncthreads();
    bf16x8 af[4], bfr[4];
#pragma unroll
    for (int mi = 0; mi < 4; mi++)
      af[mi] = *(const bf16x8*)&Al[(wr * 64 + mi * 16 + lr) * 32 + lg * 8];
#pragma unroll
    for (int ni = 0; ni < 4; ni++)
      bfr[ni] = *(const bf16x8*)&Bl[(wc * 64 + ni * 16 + lr) * 32 + lg * 8];
#pragma unroll
    for (int mi = 0; mi < 4; mi++)
#pragma unroll
      for (int ni = 0; ni < 4; ni++)
        acc[mi][ni] = __builtin_amdgcn_mfma_f32_16x16x32_bf16(
            af[mi], bfr[ni], acc[mi][ni], 0, 0, 0);
  }
#pragma unroll
  for (int mi = 0; mi < 4; mi++)
#pragma unroll
    for (int ni = 0; ni < 4; ni++) {
      int n = n0 + wc * 64 + ni * 16 + lr;
#pragma unroll
      for (int r = 0; r < 4; r++) {
        int m = m0 + wr * 64 + mi * 16 + lg * 4 + r;
        float v = acc[mi][ni][r];
        if (mode == 1 && n < 192) {
          int h = n >> 4, f = n & 15;
          int b = m >> 11, ll = m & 2047;
          Qh[((size_t)(b * NH_ + h) * L_ + ll) * F_ + f] = (__bf16)v;
        } else {
          C[(size_t)m * N + n] = v;
        }
      }
    }
}

// ---------------- chunked column sums: csum[bh][ch][80] ------------------
__global__ __launch_bounds__(128)
void scan_sum(const float* __restrict__ proj, float* __restrict__ csum) {
  int bh = blockIdx.y, ch = blockIdx.x;
  int b = bh / NH_, h = bh % NH_;
  int c = threadIdx.x;
  if (c >= 80) return;
  int off = (c < 16) ? (192 + h * 16 + c) : (384 + h * 64 + (c - 16));
  const float* src = proj + ((size_t)b * L_ + ch * CH) * NPROJ + off;
  float s = 0.f;
#pragma unroll 8
  for (int r = 0; r < CH; r++) s += src[(size_t)r * NPROJ];
  csum[((size_t)bh * NCH + ch) * 80 + c] = s;
}

// ---------------- apply: prefix base + in-chunk mean scan ----------------
__global__ __launch_bounds__(128)
void scan_apply(const float* __restrict__ proj, const float* __restrict__ csum,
                __bf16* __restrict__ CKh, __bf16* __restrict__ CVT,
                __bf16* __restrict__ Yb) {
  int bh = blockIdx.y, ch = blockIdx.x;
  int b = bh / NH_, h = bh % NH_;
  int c = threadIdx.x;
  if (c >= 80) return;
  int off = (c < 16) ? (192 + h * 16 + c) : (384 + h * 64 + (c - 16));
  const float* src = proj + ((size_t)b * L_ + ch * CH) * NPROJ + off;
  float run = 0.f;
  for (int j = 0; j < ch; j++) run += csum[((size_t)bh * NCH + j) * 80 + c];
  if (c < 16) {
    __bf16* ckp = CKh + ((size_t)bh * L_ + ch * CH) * F_ + c;
    for (int r = 0; r < CH; r++) {
      float val = src[(size_t)r * NPROJ];
      run += val;
      float mean = run / (float)(ch * CH + r + 1);
      ckp[(size_t)r * F_] = (__bf16)(val - mean);
    }
  } else {
    int d = c - 16;
    __bf16* cvp = CVT + ((size_t)bh * DH_ + d) * L_ + ch * CH;
    __bf16* yp = Yb + ((size_t)(b * L_ + ch * CH)) * DM + h * DH_ + d;
    for (int r = 0; r < CH; r++) {
      float val = src[(size_t)r * NPROJ];
      run += val;
      float mean = run / (float)(ch * CH + r + 1);
      cvp[r] = (__bf16)(val - mean);
      yp[(size_t)r * DM] = (__bf16)mean;
    }
  }
}

// ---------------- attention: KV-split waves, in-register P ---------------
// block = (bh, qtile of 32). Wave w handles p-tiles w, w+4, w+8, ...
// Swapped QK^T (mfma(CK,Q)) puts P p-slices lane-local; cvt_pk +
// permlane32_swap transposes P into PV A-fragments in-register.
// No LDS in the main loop; one slab reduction at the end.
__global__ __launch_bounds__(256)
void attn_mfma(const __bf16* __restrict__ Qh, const __bf16* __restrict__ CKh,
               const __bf16* __restrict__ CVT, __bf16* __restrict__ qkv,
               float* __restrict__ rs2) {
  __shared__ float slab[4][32][65];  // pad 65: 2-way max on write+read
  __shared__ float s2slab[4][32];
  int bh = blockIdx.y;
  int qt = (gridDim.x - 1) - blockIdx.x;  // big tiles first
  int q0 = qt * 32;
  int tid = threadIdx.x;
  int w = tid >> 6, l = tid & 63;
  int lp = l & 31, hi = l >> 5;

  // B-fragment: Q rows (n = q = q0+lp), k = f = hi*8+j
  bf16x8 qb = *(const bf16x8*)(Qh + ((size_t)bh * L_ + q0 + lp) * F_ + hi * 8);
  const __bf16* ckb = CKh + (size_t)bh * L_ * F_;
  const __bf16* cvb = CVT + (size_t)bh * DH_ * L_;

  f32x16 pv0 = {}, pv1 = {};
  float s2 = 0.f;

  for (int pt = w; pt <= qt; pt += 4) {
    int p0 = pt * 32;
    // A-fragment: CK rows (m = p = p0+lp), k = f
    bf16x8 ka = *(const bf16x8*)(ckb + (size_t)(p0 + lp) * F_ + hi * 8);
    f32x16 s = {};
    s = __builtin_amdgcn_mfma_f32_32x32x16_bf16(ka, qb, s, 0, 0, 0);
    // lane (q=lp, hi) holds P[p0+pidx][q0+lp], pidx = (reg&3)+8*(reg>>2)+4*hi
    if (pt == qt) {
#pragma unroll
      for (int reg = 0; reg < 16; reg++) {
        int pidx = (reg & 3) + 8 * (reg >> 2) + 4 * hi;
        if (pidx > lp) s[reg] = 0.f;
      }
    }
#pragma unroll
    for (int reg = 0; reg < 16; reg++) s2 = fmaf(s[reg], s[reg], s2);

    // pack + cross-half exchange -> PV A-fragments (p-major, in-register)
    unsigned w0 = cvt_pk_bf16(s[0], s[1]),   w1 = cvt_pk_bf16(s[2], s[3]);
    unsigned w2 = cvt_pk_bf16(s[4], s[5]),   w3 = cvt_pk_bf16(s[6], s[7]);
    unsigned w4 = cvt_pk_bf16(s[8], s[9]),   w5 = cvt_pk_bf16(s[10], s[11]);
    unsigned w6 = cvt_pk_bf16(s[12], s[13]), w7 = cvt_pk_bf16(s[14], s[15]);
    u32x2 r0 = __builtin_amdgcn_permlane32_swap(w0, w2, false, false);
    u32x2 r1 = __builtin_amdgcn_permlane32_swap(w1, w3, false, false);
    u32x2 r2 = __builtin_amdgcn_permlane32_swap(w4, w6, false, false);
    u32x2 r3 = __builtin_amdgcn_permlane32_swap(w5, w7, false, false);
    union { unsigned u[4]; bf16x8 v; } pa0, pa1;
    pa0.u[0] = r0[0]; pa0.u[1] = r1[0]; pa0.u[2] = r0[1]; pa0.u[3] = r1[1];
    pa1.u[0] = r2[0]; pa1.u[1] = r3[0]; pa1.u[2] = r2[1]; pa1.u[3] = r3[1];

    // PV B-fragments: CV[p][d], n = d, k = p = p0 + kt*16 + hi*8 + j
    const __bf16* cvp = cvb + p0 + hi * 8;
    bf16x8 bv00 = *(const bf16x8*)(cvp + (size_t)lp * L_);
    bf16x8 bv01 = *(const bf16x8*)(cvp + (size_t)(32 + lp) * L_);
    bf16x8 bv10 = *(const bf16x8*)(cvp + (size_t)lp * L_ + 16);
    bf16x8 bv11 = *(const bf16x8*)(cvp + (size_t)(32 + lp) * L_ + 16);
    pv0 = __builtin_amdgcn_mfma_f32_32x32x16_bf16(pa0.v, bv00, pv0, 0, 0, 0);
    pv1 = __builtin_amdgcn_mfma_f32_32x32x16_bf16(pa0.v, bv01, pv1, 0, 0, 0);
    pv0 = __builtin_amdgcn_mfma_f32_32x32x16_bf16(pa1.v, bv10, pv0, 0, 0, 0);
    pv1 = __builtin_amdgcn_mfma_f32_32x32x16_bf16(pa1.v, bv11, pv1, 0, 0, 0);
  }

  // s2: sum the two 32-lane halves (each covered half the p-rows)
  s2 += __shfl_xor(s2, 32, 64);
  if (hi == 0) s2slab[w][lp] = s2;
#pragma unroll
  for (int reg = 0; reg < 16; reg++) {
    int ql = (reg & 3) + 8 * (reg >> 2) + 4 * hi;
    slab[w][ql][lp] = pv0[reg];
    slab[w][ql][32 + lp] = pv1[reg];
  }
  __syncthreads();
  if (tid < 32) {
    float v = s2slab[0][tid] + s2slab[1][tid] + s2slab[2][tid] + s2slab[3][tid];
    rs2[(size_t)bh * L_ + q0 + tid] = v * (1.0f / 128.0f);
  }
  {
    int q = tid >> 3, seg = tid & 7;
    bf16x8 o;
#pragma unroll
    for (int j = 0; j < 8; j++) {
      int d = seg * 8 + j;
      float acc = slab[0][q][d] + slab[1][q][d] + slab[2][q][d] + slab[3][q][d];
      o[j] = (__bf16)(acc * 0.125f);
    }
    *(bf16x8*)(qkv + ((size_t)bh * L_ + q0 + q) * DH_ + seg * 8) = o;
  }
}

// ---------------- denominator scan ---------------------------------------
__global__ __launch_bounds__(256)
void denom_kernel(const float* __restrict__ rs2, float* __restrict__ denom) {
  int bh = blockIdx.x;
  int t = threadIdx.x;
  const float* rs = rs2 + (size_t)bh * L_;
  float vals[8];
  float run = 0.f;
#pragma unroll
  for (int i = 0; i < 8; i++) { run += rs[t * 8 + i]; vals[i] = run; }
  __shared__ float part[256];
  part[t] = run;
  __syncthreads();
  for (int o = 1; o < 256; o <<= 1) {
    float add = (t >= o) ? part[t - o] : 0.f;
    __syncthreads();
    part[t] += add;
    __syncthreads();
  }
  float base = (t > 0) ? part[t - 1] : 0.f;
#pragma unroll
  for (int i = 0; i < 8; i++) {
    int ll = t * 8 + i;
    denom[(size_t)bh * L_ + ll] = (float)(ll + 1) + base + vals[i];
  }
}

// ---------------- combine: Yb += qkv/denom (in place, bf16) --------------
__global__ __launch_bounds__(256)
void combine_kernel(const __bf16* __restrict__ qkv, const float* __restrict__ denom,
                    __bf16* __restrict__ Yb) {
  int bh = blockIdx.y, lt = blockIdx.x;
  int b = bh / NH_, h = bh % NH_;
  int t = threadIdx.x;
  int l0 = lt * 256;
  __shared__ float dinv[256];
  dinv[t] = 1.0f / denom[(size_t)bh * L_ + l0 + t];
  __syncthreads();
#pragma unroll
  for (int it = 0; it < 8; it++) {
    int v = it * 256 + t;
    int ll = v >> 3, d8 = v & 7;
    bf16x8 q8 = *(const bf16x8*)(qkv + ((size_t)bh * L_ + l0 + ll) * DH_ + d8 * 8);
    __bf16* yp = Yb + ((size_t)(b * L_ + l0 + ll)) * DM + h * DH_ + d8 * 8;
    bf16x8 y8 = *(const bf16x8*)yp;
    float iv = dinv[ll];
#pragma unroll
    for (int j = 0; j < 8; j++)
      y8[j] = (__bf16)((float)y8[j] + (float)q8[j] * iv);
    *(bf16x8*)yp = y8;
  }
}

extern "C" void kernel_launch(void* const* d_in, const int* in_sizes, int n_in,
                              void* d_out, int out_size, void* d_ws, size_t ws_size,
                              hipStream_t stream) {
  const float* hs = (const float*)d_in[0];
  const float* Wq = (const float*)d_in[1];
  const float* Wk = (const float*)d_in[2];
  const float* Wv = (const float*)d_in[3];
  const float* Wo = (const float*)d_in[4];
  float* out = (float*)d_out;
  char* w = (char*)d_ws;

  __bf16* hsb   = (__bf16*)(w);                      // 6,291,456
  __bf16* WqkvT = (__bf16*)(w + 6291456);            // 1,769,472
  __bf16* WoT   = (__bf16*)(w + 8060928);            // 1,179,648
  float*  proj  = (float*)(w + 9240576);             // 18,874,368
  __bf16* qkvb  = (__bf16*)(w + 28114944);           // 6,291,456
  __bf16* Qh    = (__bf16*)(w + 34406400);           // 1,572,864
  __bf16* CKh   = (__bf16*)(w + 35979264);           // 1,572,864
  __bf16* CVTg  = (__bf16*)(w + 37552128);           // 6,291,456
  __bf16* Yb    = (__bf16*)(w + 43843584);           // 6,291,456
  float*  rs2   = (float*)(w + 50135040);            // 98,304
  float*  denom = (float*)(w + 50233344);            // 98,304
  float*  csum  = (float*)(w + 50331648);            // 245,760

  prep_cast<<<1024, 256, 0, stream>>>(hs, Wq, Wk, Wv, Wo, hsb, WqkvT, WoT);
  dim3 g1(NPROJ / 128, (B_ * L_) / 128);
  gemm_bf16<<<g1, 256, 0, stream>>>(hsb, WqkvT, B_ * L_, NPROJ, DM, proj, Qh, 1);
  dim3 gs(NCH, B_ * NH_);
  scan_sum<<<gs, 128, 0, stream>>>(proj, csum);
  scan_apply<<<gs, 128, 0, stream>>>(proj, csum, CKh, CVTg, Yb);
  dim3 g3(L_ / 32, 24);
  attn_mfma<<<g3, 256, 0, stream>>>(Qh, CKh, CVTg, qkvb, rs2);
  denom_kernel<<<24, 256, 0, stream>>>(rs2, denom);
  dim3 g5(8, 24);
  combine_kernel<<<g5, 256, 0, stream>>>(qkvb, denom, Yb);
  dim3 g6(DM / 128, (B_ * L_) / 128);
  gemm_bf16<<<g6, 256, 0, stream>>>(Yb, WoT, B_ * L_, DM, DM, out, nullptr, 0);
}

// Round 7
// 135.586 us; speedup vs baseline: 1.3078x; 1.1659x over previous
//
#include <hip/hip_runtime.h>
#include <hip/hip_bf16.h>
#include <stdint.h>

constexpr int B_ = 2, L_ = 2048, DM = 768, NH_ = 12, F_ = 16, DH_ = 64;
constexpr int NPROJ = 1152;
constexpr int CH = 64, NCH = L_ / CH;  // scan chunking

typedef __bf16 bf16x8 __attribute__((ext_vector_type(8)));
typedef __bf16 bf16x4 __attribute__((ext_vector_type(4)));
typedef float f32x4 __attribute__((ext_vector_type(4)));
typedef float f32x16 __attribute__((ext_vector_type(16)));
typedef unsigned u32x2 __attribute__((ext_vector_type(2)));

#define GLOAD16(g, l)                                                        \
  __builtin_amdgcn_global_load_lds(                                          \
      (const __attribute__((address_space(1))) void*)(g),                    \
      (__attribute__((address_space(3))) void*)(l), 16, 0, 0)

__device__ __forceinline__ unsigned cvt_pk_bf16(float lo, float hi) {
  unsigned r;
  asm("v_cvt_pk_bf16_f32 %0, %1, %2" : "=v"(r) : "v"(lo), "v"(hi));
  return r;
}

// ---------------- cast + weight transpose --------------------------------
__global__ __launch_bounds__(256)
void prep_cast(const float* __restrict__ hs, const float* __restrict__ Wq,
               const float* __restrict__ Wk, const float* __restrict__ Wv,
               const float* __restrict__ Wo, __bf16* __restrict__ hsb,
               __bf16* __restrict__ WqkvT, __bf16* __restrict__ WoT) {
  int idx = blockIdx.x * 256 + threadIdx.x;
  int stride = gridDim.x * 256;
  for (int i = idx; i < B_ * L_ * DM; i += stride) hsb[i] = (__bf16)hs[i];
  for (int i = idx; i < NPROJ * DM; i += stride) {
    int n = i / DM, k = i % DM;
    float v;
    if (n < 192)      v = Wq[(size_t)k * 192 + n];
    else if (n < 384) v = Wk[(size_t)k * 192 + (n - 192)];
    else              v = Wv[(size_t)k * 768 + (n - 384)];
    WqkvT[i] = (__bf16)v;
  }
  for (int i = idx; i < DM * DM; i += stride) {
    int n = i / DM, k = i % DM;
    WoT[i] = (__bf16)Wo[(size_t)k * DM + n];
  }
}

// ---------------- bf16 MFMA GEMM: C(MxN) = A(MxK) @ Bt(NxK)^T ------------
__global__ __launch_bounds__(256)
void gemm_bf16(const __bf16* __restrict__ A, const __bf16* __restrict__ Bt,
               int M, int N, int K, float* __restrict__ C,
               __bf16* __restrict__ Qh, int mode) {
  __shared__ __align__(16) __bf16 Al[128 * 32];
  __shared__ __align__(16) __bf16 Bl[128 * 32];
  int tid = threadIdx.x;
  int m0 = blockIdx.y * 128, n0 = blockIdx.x * 128;
  int w = tid >> 6, l = tid & 63, lr = l & 15, lg = l >> 4;
  int wr = w >> 1, wc = w & 1;
  f32x4 acc[4][4] = {};
  const __bf16* Ab = A + (size_t)m0 * K;
  const __bf16* Bb = Bt + (size_t)n0 * K;
  for (int k0 = 0; k0 < K; k0 += 32) {
    __syncthreads();
#pragma unroll
    for (int i = 0; i < 2; i++) {
      int idx = i * 256 + tid;
      int row = idx >> 2, ch = idx & 3;
      GLOAD16(Ab + (size_t)row * K + k0 + ch * 8, &Al[idx * 8]);
    }
#pragma unroll
    for (int i = 0; i < 2; i++) {
      int idx = i * 256 + tid;
      int row = idx >> 2, ch = idx & 3;
      GLOAD16(Bb + (size_t)row * K + k0 + ch * 8, &Bl[idx * 8]);
    }
    asm volatile("s_waitcnt vmcnt(0)" ::: "memory");
    __syncthreads();
    bf16x8 af[4], bfr[4];
#pragma unroll
    for (int mi = 0; mi < 4; mi++)
      af[mi] = *(const bf16x8*)&Al[(wr * 64 + mi * 16 + lr) * 32 + lg * 8];
#pragma unroll
    for (int ni = 0; ni < 4; ni++)
      bfr[ni] = *(const bf16x8*)&Bl[(wc * 64 + ni * 16 + lr) * 32 + lg * 8];
#pragma unroll
    for (int mi = 0; mi < 4; mi++)
#pragma unroll
      for (int ni = 0; ni < 4; ni++)
        acc[mi][ni] = __builtin_amdgcn_mfma_f32_16x16x32_bf16(
            af[mi], bfr[ni], acc[mi][ni], 0, 0, 0);
  }
#pragma unroll
  for (int mi = 0; mi < 4; mi++)
#pragma unroll
    for (int ni = 0; ni < 4; ni++) {
      int n = n0 + wc * 64 + ni * 16 + lr;
#pragma unroll
      for (int r = 0; r < 4; r++) {
        int m = m0 + wr * 64 + mi * 16 + lg * 4 + r;
        float v = acc[mi][ni][r];
        if (mode == 1 && n < 192) {
          int h = n >> 4, f = n & 15;
          int b = m >> 11, ll = m & 2047;
          Qh[((size_t)(b * NH_ + h) * L_ + ll) * F_ + f] = (__bf16)v;
        } else {
          C[(size_t)m * N + n] = v;
        }
      }
    }
}

// ---------------- chunked column sums: csum[bh][ch][80] ------------------
__global__ __launch_bounds__(128)
void scan_sum(const float* __restrict__ proj, float* __restrict__ csum) {
  int bh = blockIdx.y, ch = blockIdx.x;
  int b = bh / NH_, h = bh % NH_;
  int c = threadIdx.x;
  if (c >= 80) return;
  int off = (c < 16) ? (192 + h * 16 + c) : (384 + h * 64 + (c - 16));
  const float* src = proj + ((size_t)b * L_ + ch * CH) * NPROJ + off;
  float s = 0.f;
#pragma unroll 8
  for (int r = 0; r < CH; r++) s += src[(size_t)r * NPROJ];
  csum[((size_t)bh * NCH + ch) * 80 + c] = s;
}

// ---------------- apply: prefix base + in-chunk mean scan ----------------
// CVf fragment-native layout: element (d, p) at [bh][p>>4][d][p&15].
__global__ __launch_bounds__(128)
void scan_apply(const float* __restrict__ proj, const float* __restrict__ csum,
                __bf16* __restrict__ CKh, __bf16* __restrict__ CVf,
                __bf16* __restrict__ Yb) {
  int bh = blockIdx.y, ch = blockIdx.x;
  int b = bh / NH_, h = bh % NH_;
  int c = threadIdx.x;
  if (c >= 80) return;
  int off = (c < 16) ? (192 + h * 16 + c) : (384 + h * 64 + (c - 16));
  const float* src = proj + ((size_t)b * L_ + ch * CH) * NPROJ + off;
  float run = 0.f;
  for (int j = 0; j < ch; j++) run += csum[((size_t)bh * NCH + j) * 80 + c];
  if (c < 16) {
    __bf16* ckp = CKh + ((size_t)bh * L_ + ch * CH) * F_ + c;
    for (int r = 0; r < CH; r++) {
      float val = src[(size_t)r * NPROJ];
      run += val;
      float mean = run / (float)(ch * CH + r + 1);
      ckp[(size_t)r * F_] = (__bf16)(val - mean);
    }
  } else {
    int d = c - 16;
    __bf16* cvbase = CVf + (size_t)bh * 128 * 1024;  // 128 chunks x 64 d x 16
    __bf16* yp = Yb + ((size_t)(b * L_ + ch * CH)) * DM + h * DH_ + d;
    for (int r = 0; r < CH; r++) {
      float val = src[(size_t)r * NPROJ];
      run += val;
      int p = ch * CH + r;
      float mean = run / (float)(p + 1);
      cvbase[(size_t)(p >> 4) * 1024 + d * 16 + (p & 15)] = (__bf16)(val - mean);
      yp[(size_t)r * DM] = (__bf16)mean;
    }
  }
}

// ---------------- attention: KV-split waves, in-register P ---------------
// block = (bh, qtile of 32). Wave w handles p-tiles w, w+4, w+8, ...
// Swapped QK^T (mfma(CK,Q)) puts P p-slices lane-local; cvt_pk +
// permlane32_swap transposes P into PV A-fragments in-register.
// CV read from fragment-native CVf (fully coalesced 16B/lane).
__global__ __launch_bounds__(256)
void attn_mfma(const __bf16* __restrict__ Qh, const __bf16* __restrict__ CKh,
               const __bf16* __restrict__ CVf, __bf16* __restrict__ qkv,
               float* __restrict__ rs2) {
  __shared__ float slab[4][32][65];
  __shared__ float s2slab[4][32];
  int bh = blockIdx.y;
  int qt = (gridDim.x - 1) - blockIdx.x;  // big tiles first
  int q0 = qt * 32;
  int tid = threadIdx.x;
  int w = tid >> 6, l = tid & 63;
  int lp = l & 31, hi = l >> 5;

  // B-fragment: Q rows (n = q = q0+lp), k = f = hi*8+j
  bf16x8 qb = *(const bf16x8*)(Qh + ((size_t)bh * L_ + q0 + lp) * F_ + hi * 8);
  const __bf16* ckb = CKh + (size_t)bh * L_ * F_;
  const __bf16* cvb = CVf + (size_t)bh * 128 * 1024;

  f32x16 pv0 = {}, pv1 = {};
  float s2 = 0.f;

  for (int pt = w; pt <= qt; pt += 4) {
    int p0 = pt * 32;
    // A-fragment: CK rows (m = p = p0+lp), k = f
    bf16x8 ka = *(const bf16x8*)(ckb + (size_t)(p0 + lp) * F_ + hi * 8);
    f32x16 s = {};
    s = __builtin_amdgcn_mfma_f32_32x32x16_bf16(ka, qb, s, 0, 0, 0);
    // lane (q=lp, hi) holds P[p0+pidx][q0+lp], pidx = (reg&3)+8*(reg>>2)+4*hi
    if (pt == qt) {
#pragma unroll
      for (int reg = 0; reg < 16; reg++) {
        int pidx = (reg & 3) + 8 * (reg >> 2) + 4 * hi;
        if (pidx > lp) s[reg] = 0.f;
      }
    }
#pragma unroll
    for (int reg = 0; reg < 16; reg++) s2 = fmaf(s[reg], s[reg], s2);

    // pack + cross-half exchange -> PV A-fragments (p-major, in-register)
    unsigned w0 = cvt_pk_bf16(s[0], s[1]),   w1 = cvt_pk_bf16(s[2], s[3]);
    unsigned w2 = cvt_pk_bf16(s[4], s[5]),   w3 = cvt_pk_bf16(s[6], s[7]);
    unsigned w4 = cvt_pk_bf16(s[8], s[9]),   w5 = cvt_pk_bf16(s[10], s[11]);
    unsigned w6 = cvt_pk_bf16(s[12], s[13]), w7 = cvt_pk_bf16(s[14], s[15]);
    u32x2 r0 = __builtin_amdgcn_permlane32_swap(w0, w2, false, false);
    u32x2 r1 = __builtin_amdgcn_permlane32_swap(w1, w3, false, false);
    u32x2 r2 = __builtin_amdgcn_permlane32_swap(w4, w6, false, false);
    u32x2 r3 = __builtin_amdgcn_permlane32_swap(w5, w7, false, false);
    union { unsigned u[4]; bf16x8 v; } pa0, pa1;
    pa0.u[0] = r0[0]; pa0.u[1] = r1[0]; pa0.u[2] = r0[1]; pa0.u[3] = r1[1];
    pa1.u[0] = r2[0]; pa1.u[1] = r3[0]; pa1.u[2] = r2[1]; pa1.u[3] = r3[1];

    // PV B-fragments from CVf: chunk c0 = 2*pt (p0..p0+15), c0+1 (p0+16..31)
    // lane l: d = lp (+32), k-slice j at d*16 + hi*8 -> 16B contiguous
    const __bf16* cvp = cvb + (size_t)(2 * pt) * 1024 + lp * 16 + hi * 8;
    bf16x8 bv00 = *(const bf16x8*)(cvp);
    bf16x8 bv01 = *(const bf16x8*)(cvp + 512);         // d + 32
    bf16x8 bv10 = *(const bf16x8*)(cvp + 1024);        // next 16-chunk
    bf16x8 bv11 = *(const bf16x8*)(cvp + 1536);
    pv0 = __builtin_amdgcn_mfma_f32_32x32x16_bf16(pa0.v, bv00, pv0, 0, 0, 0);
    pv1 = __builtin_amdgcn_mfma_f32_32x32x16_bf16(pa0.v, bv01, pv1, 0, 0, 0);
    pv0 = __builtin_amdgcn_mfma_f32_32x32x16_bf16(pa1.v, bv10, pv0, 0, 0, 0);
    pv1 = __builtin_amdgcn_mfma_f32_32x32x16_bf16(pa1.v, bv11, pv1, 0, 0, 0);
  }

  // s2: sum the two 32-lane halves (each covered half the p-rows)
  s2 += __shfl_xor(s2, 32, 64);
  if (hi == 0) s2slab[w][lp] = s2;
#pragma unroll
  for (int reg = 0; reg < 16; reg++) {
    int ql = (reg & 3) + 8 * (reg >> 2) + 4 * hi;
    slab[w][ql][lp] = pv0[reg];
    slab[w][ql][32 + lp] = pv1[reg];
  }
  __syncthreads();
  if (tid < 32) {
    float v = s2slab[0][tid] + s2slab[1][tid] + s2slab[2][tid] + s2slab[3][tid];
    rs2[(size_t)bh * L_ + q0 + tid] = v * (1.0f / 128.0f);
  }
  {
    int q = tid >> 3, seg = tid & 7;
    bf16x8 o;
#pragma unroll
    for (int j = 0; j < 8; j++) {
      int d = seg * 8 + j;
      float acc = slab[0][q][d] + slab[1][q][d] + slab[2][q][d] + slab[3][q][d];
      o[j] = (__bf16)(acc * 0.125f);
    }
    *(bf16x8*)(qkv + ((size_t)bh * L_ + q0 + q) * DH_ + seg * 8) = o;
  }
}

// ---------------- denominator scan ---------------------------------------
__global__ __launch_bounds__(256)
void denom_kernel(const float* __restrict__ rs2, float* __restrict__ denom) {
  int bh = blockIdx.x;
  int t = threadIdx.x;
  const float* rs = rs2 + (size_t)bh * L_;
  float vals[8];
  float run = 0.f;
#pragma unroll
  for (int i = 0; i < 8; i++) { run += rs[t * 8 + i]; vals[i] = run; }
  __shared__ float part[256];
  part[t] = run;
  __syncthreads();
  for (int o = 1; o < 256; o <<= 1) {
    float add = (t >= o) ? part[t - o] : 0.f;
    __syncthreads();
    part[t] += add;
    __syncthreads();
  }
  float base = (t > 0) ? part[t - 1] : 0.f;
#pragma unroll
  for (int i = 0; i < 8; i++) {
    int ll = t * 8 + i;
    denom[(size_t)bh * L_ + ll] = (float)(ll + 1) + base + vals[i];
  }
}

// ---------------- combine: Yb += qkv/denom (in place, bf16) --------------
__global__ __launch_bounds__(256)
void combine_kernel(const __bf16* __restrict__ qkv, const float* __restrict__ denom,
                    __bf16* __restrict__ Yb) {
  int bh = blockIdx.y, lt = blockIdx.x;
  int b = bh / NH_, h = bh % NH_;
  int t = threadIdx.x;
  int l0 = lt * 256;
  __shared__ float dinv[256];
  dinv[t] = 1.0f / denom[(size_t)bh * L_ + l0 + t];
  __syncthreads();
#pragma unroll
  for (int it = 0; it < 8; it++) {
    int v = it * 256 + t;
    int ll = v >> 3, d8 = v & 7;
    bf16x8 q8 = *(const bf16x8*)(qkv + ((size_t)bh * L_ + l0 + ll) * DH_ + d8 * 8);
    __bf16* yp = Yb + ((size_t)(b * L_ + l0 + ll)) * DM + h * DH_ + d8 * 8;
    bf16x8 y8 = *(const bf16x8*)yp;
    float iv = dinv[ll];
#pragma unroll
    for (int j = 0; j < 8; j++)
      y8[j] = (__bf16)((float)y8[j] + (float)q8[j] * iv);
    *(bf16x8*)yp = y8;
  }
}

extern "C" void kernel_launch(void* const* d_in, const int* in_sizes, int n_in,
                              void* d_out, int out_size, void* d_ws, size_t ws_size,
                              hipStream_t stream) {
  const float* hs = (const float*)d_in[0];
  const float* Wq = (const float*)d_in[1];
  const float* Wk = (const float*)d_in[2];
  const float* Wv = (const float*)d_in[3];
  const float* Wo = (const float*)d_in[4];
  float* out = (float*)d_out;
  char* w = (char*)d_ws;

  __bf16* hsb   = (__bf16*)(w);                      // 6,291,456
  __bf16* WqkvT = (__bf16*)(w + 6291456);            // 1,769,472
  __bf16* WoT   = (__bf16*)(w + 8060928);            // 1,179,648
  float*  proj  = (float*)(w + 9240576);             // 18,874,368
  __bf16* qkvb  = (__bf16*)(w + 28114944);           // 6,291,456
  __bf16* Qh    = (__bf16*)(w + 34406400);           // 1,572,864
  __bf16* CKh   = (__bf16*)(w + 35979264);           // 1,572,864
  __bf16* CVfg  = (__bf16*)(w + 37552128);           // 6,291,456
  __bf16* Yb    = (__bf16*)(w + 43843584);           // 6,291,456
  float*  rs2   = (float*)(w + 50135040);            // 98,304
  float*  denom = (float*)(w + 50233344);            // 98,304
  float*  csum  = (float*)(w + 50331648);            // 245,760

  prep_cast<<<1024, 256, 0, stream>>>(hs, Wq, Wk, Wv, Wo, hsb, WqkvT, WoT);
  dim3 g1(NPROJ / 128, (B_ * L_) / 128);
  gemm_bf16<<<g1, 256, 0, stream>>>(hsb, WqkvT, B_ * L_, NPROJ, DM, proj, Qh, 1);
  dim3 gs(NCH, B_ * NH_);
  scan_sum<<<gs, 128, 0, stream>>>(proj, csum);
  scan_apply<<<gs, 128, 0, stream>>>(proj, csum, CKh, CVfg, Yb);
  dim3 g3(L_ / 32, 24);
  attn_mfma<<<g3, 256, 0, stream>>>(Qh, CKh, CVfg, qkvb, rs2);
  denom_kernel<<<24, 256, 0, stream>>>(rs2, denom);
  dim3 g5(8, 24);
  combine_kernel<<<g5, 256, 0, stream>>>(qkvb, denom, Yb);
  dim3 g6(DM / 128, (B_ * L_) / 128);
  gemm_bf16<<<g6, 256, 0, stream>>>(Yb, WoT, B_ * L_, DM, DM, out, nullptr, 0);
}

// Round 8
// 134.978 us; speedup vs baseline: 1.3137x; 1.0045x over previous
//
#include <hip/hip_runtime.h>
#include <hip/hip_bf16.h>
#include <stdint.h>

constexpr int B_ = 2, L_ = 2048, DM = 768, NH_ = 12, F_ = 16, DH_ = 64;
constexpr int NPROJ = 1152;
constexpr int CH = 64, NCH = L_ / CH;  // scan chunking (64-row chunks)

typedef __bf16 bf16x8 __attribute__((ext_vector_type(8)));
typedef __bf16 bf16x4 __attribute__((ext_vector_type(4)));
typedef float f32x4 __attribute__((ext_vector_type(4)));
typedef float f32x16 __attribute__((ext_vector_type(16)));
typedef unsigned u32x2 __attribute__((ext_vector_type(2)));

#define GLOAD16(g, l)                                                        \
  __builtin_amdgcn_global_load_lds(                                          \
      (const __attribute__((address_space(1))) void*)(g),                    \
      (__attribute__((address_space(3))) void*)(l), 16, 0, 0)

__device__ __forceinline__ unsigned cvt_pk_bf16(float lo, float hi) {
  unsigned r;
  asm("v_cvt_pk_bf16_f32 %0, %1, %2" : "=v"(r) : "v"(lo), "v"(hi));
  return r;
}

// ---------------- cast + weight transpose --------------------------------
__global__ __launch_bounds__(256)
void prep_cast(const float* __restrict__ hs, const float* __restrict__ Wq,
               const float* __restrict__ Wk, const float* __restrict__ Wv,
               const float* __restrict__ Wo, __bf16* __restrict__ hsb,
               __bf16* __restrict__ WqkvT, __bf16* __restrict__ WoT) {
  int idx = blockIdx.x * 256 + threadIdx.x;
  int stride = gridDim.x * 256;
  for (int i = idx; i < B_ * L_ * DM; i += stride) hsb[i] = (__bf16)hs[i];
  for (int i = idx; i < NPROJ * DM; i += stride) {
    int n = i / DM, k = i % DM;
    float v;
    if (n < 192)      v = Wq[(size_t)k * 192 + n];
    else if (n < 384) v = Wk[(size_t)k * 192 + (n - 192)];
    else              v = Wv[(size_t)k * 768 + (n - 384)];
    WqkvT[i] = (__bf16)v;
  }
  for (int i = idx; i < DM * DM; i += stride) {
    int n = i / DM, k = i % DM;
    WoT[i] = (__bf16)Wo[(size_t)k * DM + n];
  }
}

// ---------------- bf16 MFMA GEMM: C(MxN) = A(MxK) @ Bt(NxK)^T ------------
// mode 1 (projection pass): q-columns (n<192) go bf16 to Qh, and the
// epilogue reduces per-64-row-chunk column sums of k/v columns into csum.
__global__ __launch_bounds__(256)
void gemm_bf16(const __bf16* __restrict__ A, const __bf16* __restrict__ Bt,
               int M, int N, int K, float* __restrict__ C,
               __bf16* __restrict__ Qh, float* __restrict__ csum, int mode) {
  __shared__ __align__(16) __bf16 Al[128 * 32];
  __shared__ __align__(16) __bf16 Bl[128 * 32];
  __shared__ float csl[2][128];
  int tid = threadIdx.x;
  int m0 = blockIdx.y * 128, n0 = blockIdx.x * 128;
  int w = tid >> 6, l = tid & 63, lr = l & 15, lg = l >> 4;
  int wr = w >> 1, wc = w & 1;
  f32x4 acc[4][4] = {};
  const __bf16* Ab = A + (size_t)m0 * K;
  const __bf16* Bb = Bt + (size_t)n0 * K;
  for (int k0 = 0; k0 < K; k0 += 32) {
    __syncthreads();
#pragma unroll
    for (int i = 0; i < 2; i++) {
      int idx = i * 256 + tid;
      int row = idx >> 2, ch = idx & 3;
      GLOAD16(Ab + (size_t)row * K + k0 + ch * 8, &Al[idx * 8]);
    }
#pragma unroll
    for (int i = 0; i < 2; i++) {
      int idx = i * 256 + tid;
      int row = idx >> 2, ch = idx & 3;
      GLOAD16(Bb + (size_t)row * K + k0 + ch * 8, &Bl[idx * 8]);
    }
    asm volatile("s_waitcnt vmcnt(0)" ::: "memory");
    __syncthreads();
    bf16x8 af[4], bfr[4];
#pragma unroll
    for (int mi = 0; mi < 4; mi++)
      af[mi] = *(const bf16x8*)&Al[(wr * 64 + mi * 16 + lr) * 32 + lg * 8];
#pragma unroll
    for (int ni = 0; ni < 4; ni++)
      bfr[ni] = *(const bf16x8*)&Bl[(wc * 64 + ni * 16 + lr) * 32 + lg * 8];
#pragma unroll
    for (int mi = 0; mi < 4; mi++)
#pragma unroll
      for (int ni = 0; ni < 4; ni++)
        acc[mi][ni] = __builtin_amdgcn_mfma_f32_16x16x32_bf16(
            af[mi], bfr[ni], acc[mi][ni], 0, 0, 0);
  }
#pragma unroll
  for (int mi = 0; mi < 4; mi++)
#pragma unroll
    for (int ni = 0; ni < 4; ni++) {
      int n = n0 + wc * 64 + ni * 16 + lr;
#pragma unroll
      for (int r = 0; r < 4; r++) {
        int m = m0 + wr * 64 + mi * 16 + lg * 4 + r;
        float v = acc[mi][ni][r];
        if (mode == 1 && n < 192) {
          int h = n >> 4, f = n & 15;
          int b = m >> 11, ll = m & 2047;
          Qh[((size_t)(b * NH_ + h) * L_ + ll) * F_ + f] = (__bf16)v;
        } else {
          C[(size_t)m * N + n] = v;
        }
      }
    }
  if (mode == 1) {
    // column sums over each 64-row half of this tile (chunk granularity 64)
#pragma unroll
    for (int ni = 0; ni < 4; ni++) {
      float cs = 0.f;
#pragma unroll
      for (int mi = 0; mi < 4; mi++)
#pragma unroll
        for (int r = 0; r < 4; r++) cs += acc[mi][ni][r];
      cs += __shfl_xor(cs, 16, 64);
      cs += __shfl_xor(cs, 32, 64);
      if (lg == 0) csl[wr][wc * 64 + ni * 16 + lr] = cs;
    }
    __syncthreads();
    int colg = tid & 127, half = tid >> 7;
    int n = n0 + colg;
    if (n >= 192) {
      int b = m0 >> 11;
      int ch64 = ((m0 & 2047) >> 6) + half;
      float v = csl[half][colg];
      int h, c;
      if (n < 384) { h = (n - 192) >> 4; c = (n - 192) & 15; }
      else         { h = (n - 384) >> 6; c = 16 + ((n - 384) & 63); }
      csum[((size_t)(b * NH_ + h) * NCH + ch64) * 80 + c] = v;
    }
  }
}

// ---------------- apply: prefix base + in-chunk mean scan ----------------
// CVf fragment-native layout: element (d, p) at [bh][p>>4][d][p&15].
__global__ __launch_bounds__(128)
void scan_apply(const float* __restrict__ proj, const float* __restrict__ csum,
                __bf16* __restrict__ CKh, __bf16* __restrict__ CVf,
                __bf16* __restrict__ Yb) {
  int bh = blockIdx.y, ch = blockIdx.x;
  int b = bh / NH_, h = bh % NH_;
  int c = threadIdx.x;
  if (c >= 80) return;
  int off = (c < 16) ? (192 + h * 16 + c) : (384 + h * 64 + (c - 16));
  const float* src = proj + ((size_t)b * L_ + ch * CH) * NPROJ + off;
  float run = 0.f;
  for (int j = 0; j < ch; j++) run += csum[((size_t)bh * NCH + j) * 80 + c];
  if (c < 16) {
    __bf16* ckp = CKh + ((size_t)bh * L_ + ch * CH) * F_ + c;
    for (int r = 0; r < CH; r++) {
      float val = src[(size_t)r * NPROJ];
      run += val;
      float mean = run / (float)(ch * CH + r + 1);
      ckp[(size_t)r * F_] = (__bf16)(val - mean);
    }
  } else {
    int d = c - 16;
    __bf16* cvbase = CVf + (size_t)bh * 128 * 1024;  // 128 chunks x 64 d x 16
    __bf16* yp = Yb + ((size_t)(b * L_ + ch * CH)) * DM + h * DH_ + d;
    for (int r = 0; r < CH; r++) {
      float val = src[(size_t)r * NPROJ];
      run += val;
      int p = ch * CH + r;
      float mean = run / (float)(p + 1);
      cvbase[(size_t)(p >> 4) * 1024 + d * 16 + (p & 15)] = (__bf16)(val - mean);
      yp[(size_t)r * DM] = (__bf16)mean;
    }
  }
}

// ---------------- attention: KV-split waves, in-register P, ILP-2 --------
// block = (bh, qtile of 32). Wave w handles p-tile pairs {8k+2w, 8k+2w+1}.
// Swapped QK^T + cvt_pk/permlane32_swap transpose keeps P in registers.
__global__ __launch_bounds__(256)
void attn_mfma(const __bf16* __restrict__ Qh, const __bf16* __restrict__ CKh,
               const __bf16* __restrict__ CVf, __bf16* __restrict__ qkv,
               float* __restrict__ rs2) {
  __shared__ float slab[4][32][65];
  __shared__ float s2slab[4][32];
  int bh = blockIdx.y;
  int qt = (gridDim.x - 1) - blockIdx.x;  // big tiles first
  int q0 = qt * 32;
  int tid = threadIdx.x;
  int w = tid >> 6, l = tid & 63;
  int lp = l & 31, hi = l >> 5;

  bf16x8 qb = *(const bf16x8*)(Qh + ((size_t)bh * L_ + q0 + lp) * F_ + hi * 8);
  const __bf16* ckb = CKh + (size_t)bh * L_ * F_;
  const __bf16* cvb = CVf + (size_t)bh * 128 * 1024;

  f32x16 pv0 = {}, pv1 = {};
  float s2 = 0.f;

  for (int base = 2 * w; base <= qt; base += 8) {
    int t0 = base;
    bool has2 = (base + 1 <= qt);
    int t1 = has2 ? base + 1 : qt;  // clamp: safe finite data
    bf16x8 ka0 = *(const bf16x8*)(ckb + (size_t)(t0 * 32 + lp) * F_ + hi * 8);
    bf16x8 ka1 = *(const bf16x8*)(ckb + (size_t)(t1 * 32 + lp) * F_ + hi * 8);
    f32x16 s0 = {}, s1 = {};
    s0 = __builtin_amdgcn_mfma_f32_32x32x16_bf16(ka0, qb, s0, 0, 0, 0);
    s1 = __builtin_amdgcn_mfma_f32_32x32x16_bf16(ka1, qb, s1, 0, 0, 0);
    if (t0 == qt) {
#pragma unroll
      for (int reg = 0; reg < 16; reg++) {
        int pidx = (reg & 3) + 8 * (reg >> 2) + 4 * hi;
        if (pidx > lp) s0[reg] = 0.f;
      }
    }
    if (t1 == qt) {
#pragma unroll
      for (int reg = 0; reg < 16; reg++) {
        int pidx = (reg & 3) + 8 * (reg >> 2) + 4 * hi;
        if (pidx > lp) s1[reg] = 0.f;
      }
    }
    if (!has2) {
#pragma unroll
      for (int reg = 0; reg < 16; reg++) s1[reg] = 0.f;
    }
#pragma unroll
    for (int reg = 0; reg < 16; reg++) s2 = fmaf(s0[reg], s0[reg], s2);
#pragma unroll
    for (int reg = 0; reg < 16; reg++) s2 = fmaf(s1[reg], s1[reg], s2);

    // pack + cross-half exchange -> PV A-fragments, tile 0
    unsigned a0 = cvt_pk_bf16(s0[0], s0[1]),   a1 = cvt_pk_bf16(s0[2], s0[3]);
    unsigned a2 = cvt_pk_bf16(s0[4], s0[5]),   a3 = cvt_pk_bf16(s0[6], s0[7]);
    unsigned a4 = cvt_pk_bf16(s0[8], s0[9]),   a5 = cvt_pk_bf16(s0[10], s0[11]);
    unsigned a6 = cvt_pk_bf16(s0[12], s0[13]), a7 = cvt_pk_bf16(s0[14], s0[15]);
    u32x2 ra0 = __builtin_amdgcn_permlane32_swap(a0, a2, false, false);
    u32x2 ra1 = __builtin_amdgcn_permlane32_swap(a1, a3, false, false);
    u32x2 ra2 = __builtin_amdgcn_permlane32_swap(a4, a6, false, false);
    u32x2 ra3 = __builtin_amdgcn_permlane32_swap(a5, a7, false, false);
    union { unsigned u[4]; bf16x8 v; } pa00, pa01, pa10, pa11;
    pa00.u[0] = ra0[0]; pa00.u[1] = ra1[0]; pa00.u[2] = ra0[1]; pa00.u[3] = ra1[1];
    pa01.u[0] = ra2[0]; pa01.u[1] = ra3[0]; pa01.u[2] = ra2[1]; pa01.u[3] = ra3[1];
    // tile 1
    unsigned b0 = cvt_pk_bf16(s1[0], s1[1]),   b1 = cvt_pk_bf16(s1[2], s1[3]);
    unsigned b2 = cvt_pk_bf16(s1[4], s1[5]),   b3 = cvt_pk_bf16(s1[6], s1[7]);
    unsigned b4 = cvt_pk_bf16(s1[8], s1[9]),   b5 = cvt_pk_bf16(s1[10], s1[11]);
    unsigned b6 = cvt_pk_bf16(s1[12], s1[13]), b7 = cvt_pk_bf16(s1[14], s1[15]);
    u32x2 rb0 = __builtin_amdgcn_permlane32_swap(b0, b2, false, false);
    u32x2 rb1 = __builtin_amdgcn_permlane32_swap(b1, b3, false, false);
    u32x2 rb2 = __builtin_amdgcn_permlane32_swap(b4, b6, false, false);
    u32x2 rb3 = __builtin_amdgcn_permlane32_swap(b5, b7, false, false);
    pa10.u[0] = rb0[0]; pa10.u[1] = rb1[0]; pa10.u[2] = rb0[1]; pa10.u[3] = rb1[1];
    pa11.u[0] = rb2[0]; pa11.u[1] = rb3[0]; pa11.u[2] = rb2[1]; pa11.u[3] = rb3[1];

    // PV B-fragments from CVf (fragment-native, 16B/lane coalesced)
    const __bf16* cvp0 = cvb + (size_t)(2 * t0) * 1024 + lp * 16 + hi * 8;
    const __bf16* cvp1 = cvb + (size_t)(2 * t1) * 1024 + lp * 16 + hi * 8;
    bf16x8 bv00 = *(const bf16x8*)(cvp0);
    bf16x8 bv01 = *(const bf16x8*)(cvp0 + 512);
    bf16x8 bv02 = *(const bf16x8*)(cvp0 + 1024);
    bf16x8 bv03 = *(const bf16x8*)(cvp0 + 1536);
    bf16x8 bv10 = *(const bf16x8*)(cvp1);
    bf16x8 bv11 = *(const bf16x8*)(cvp1 + 512);
    bf16x8 bv12 = *(const bf16x8*)(cvp1 + 1024);
    bf16x8 bv13 = *(const bf16x8*)(cvp1 + 1536);
    pv0 = __builtin_amdgcn_mfma_f32_32x32x16_bf16(pa00.v, bv00, pv0, 0, 0, 0);
    pv1 = __builtin_amdgcn_mfma_f32_32x32x16_bf16(pa00.v, bv01, pv1, 0, 0, 0);
    pv0 = __builtin_amdgcn_mfma_f32_32x32x16_bf16(pa01.v, bv02, pv0, 0, 0, 0);
    pv1 = __builtin_amdgcn_mfma_f32_32x32x16_bf16(pa01.v, bv03, pv1, 0, 0, 0);
    pv0 = __builtin_amdgcn_mfma_f32_32x32x16_bf16(pa10.v, bv10, pv0, 0, 0, 0);
    pv1 = __builtin_amdgcn_mfma_f32_32x32x16_bf16(pa10.v, bv11, pv1, 0, 0, 0);
    pv0 = __builtin_amdgcn_mfma_f32_32x32x16_bf16(pa11.v, bv12, pv0, 0, 0, 0);
    pv1 = __builtin_amdgcn_mfma_f32_32x32x16_bf16(pa11.v, bv13, pv1, 0, 0, 0);
  }

  // s2: sum the two 32-lane halves (each covered half the p-rows)
  s2 += __shfl_xor(s2, 32, 64);
  if (hi == 0) s2slab[w][lp] = s2;
#pragma unroll
  for (int reg = 0; reg < 16; reg++) {
    int ql = (reg & 3) + 8 * (reg >> 2) + 4 * hi;
    slab[w][ql][lp] = pv0[reg];
    slab[w][ql][32 + lp] = pv1[reg];
  }
  __syncthreads();
  if (tid < 32) {
    float v = s2slab[0][tid] + s2slab[1][tid] + s2slab[2][tid] + s2slab[3][tid];
    rs2[(size_t)bh * L_ + q0 + tid] = v * (1.0f / 128.0f);
  }
  {
    int q = tid >> 3, seg = tid & 7;
    bf16x8 o;
#pragma unroll
    for (int j = 0; j < 8; j++) {
      int d = seg * 8 + j;
      float acc = slab[0][q][d] + slab[1][q][d] + slab[2][q][d] + slab[3][q][d];
      o[j] = (__bf16)(acc * 0.125f);
    }
    *(bf16x8*)(qkv + ((size_t)bh * L_ + q0 + q) * DH_ + seg * 8) = o;
  }
}

// ---------------- denominator scan ---------------------------------------
__global__ __launch_bounds__(256)
void denom_kernel(const float* __restrict__ rs2, float* __restrict__ denom) {
  int bh = blockIdx.x;
  int t = threadIdx.x;
  const float* rs = rs2 + (size_t)bh * L_;
  float vals[8];
  float run = 0.f;
#pragma unroll
  for (int i = 0; i < 8; i++) { run += rs[t * 8 + i]; vals[i] = run; }
  __shared__ float part[256];
  part[t] = run;
  __syncthreads();
  for (int o = 1; o < 256; o <<= 1) {
    float add = (t >= o) ? part[t - o] : 0.f;
    __syncthreads();
    part[t] += add;
    __syncthreads();
  }
  float base = (t > 0) ? part[t - 1] : 0.f;
#pragma unroll
  for (int i = 0; i < 8; i++) {
    int ll = t * 8 + i;
    denom[(size_t)bh * L_ + ll] = (float)(ll + 1) + base + vals[i];
  }
}

// ---------------- combine: Yb += qkv/denom (in place, bf16) --------------
__global__ __launch_bounds__(256)
void combine_kernel(const __bf16* __restrict__ qkv, const float* __restrict__ denom,
                    __bf16* __restrict__ Yb) {
  int bh = blockIdx.y, lt = blockIdx.x;
  int b = bh / NH_, h = bh % NH_;
  int t = threadIdx.x;
  int l0 = lt * 256;
  __shared__ float dinv[256];
  dinv[t] = 1.0f / denom[(size_t)bh * L_ + l0 + t];
  __syncthreads();
#pragma unroll
  for (int it = 0; it < 8; it++) {
    int v = it * 256 + t;
    int ll = v >> 3, d8 = v & 7;
    bf16x8 q8 = *(const bf16x8*)(qkv + ((size_t)bh * L_ + l0 + ll) * DH_ + d8 * 8);
    __bf16* yp = Yb + ((size_t)(b * L_ + l0 + ll)) * DM + h * DH_ + d8 * 8;
    bf16x8 y8 = *(const bf16x8*)yp;
    float iv = dinv[ll];
#pragma unroll
    for (int j = 0; j < 8; j++)
      y8[j] = (__bf16)((float)y8[j] + (float)q8[j] * iv);
    *(bf16x8*)yp = y8;
  }
}

extern "C" void kernel_launch(void* const* d_in, const int* in_sizes, int n_in,
                              void* d_out, int out_size, void* d_ws, size_t ws_size,
                              hipStream_t stream) {
  const float* hs = (const float*)d_in[0];
  const float* Wq = (const float*)d_in[1];
  const float* Wk = (const float*)d_in[2];
  const float* Wv = (const float*)d_in[3];
  const float* Wo = (const float*)d_in[4];
  float* out = (float*)d_out;
  char* w = (char*)d_ws;

  __bf16* hsb   = (__bf16*)(w);                      // 6,291,456
  __bf16* WqkvT = (__bf16*)(w + 6291456);            // 1,769,472
  __bf16* WoT   = (__bf16*)(w + 8060928);            // 1,179,648
  float*  proj  = (float*)(w + 9240576);             // 18,874,368
  __bf16* qkvb  = (__bf16*)(w + 28114944);           // 6,291,456
  __bf16* Qh    = (__bf16*)(w + 34406400);           // 1,572,864
  __bf16* CKh   = (__bf16*)(w + 35979264);           // 1,572,864
  __bf16* CVfg  = (__bf16*)(w + 37552128);           // 6,291,456
  __bf16* Yb    = (__bf16*)(w + 43843584);           // 6,291,456
  float*  rs2   = (float*)(w + 50135040);            // 98,304
  float*  denom = (float*)(w + 50233344);            // 98,304
  float*  csum  = (float*)(w + 50331648);            // 245,760

  prep_cast<<<1024, 256, 0, stream>>>(hs, Wq, Wk, Wv, Wo, hsb, WqkvT, WoT);
  dim3 g1(NPROJ / 128, (B_ * L_) / 128);
  gemm_bf16<<<g1, 256, 0, stream>>>(hsb, WqkvT, B_ * L_, NPROJ, DM, proj, Qh, csum, 1);
  dim3 gs(NCH, B_ * NH_);
  scan_apply<<<gs, 128, 0, stream>>>(proj, csum, CKh, CVfg, Yb);
  dim3 g3(L_ / 32, 24);
  attn_mfma<<<g3, 256, 0, stream>>>(Qh, CKh, CVfg, qkvb, rs2);
  denom_kernel<<<24, 256, 0, stream>>>(rs2, denom);
  dim3 g5(8, 24);
  combine_kernel<<<g5, 256, 0, stream>>>(qkvb, denom, Yb);
  dim3 g6(DM / 128, (B_ * L_) / 128);
  gemm_bf16<<<g6, 256, 0, stream>>>(Yb, WoT, B_ * L_, DM, DM, out, nullptr, nullptr, 0);
}

// Round 9
// 132.251 us; speedup vs baseline: 1.3408x; 1.0206x over previous
//
#include <hip/hip_runtime.h>
#include <hip/hip_bf16.h>
#include <stdint.h>

constexpr int B_ = 2, L_ = 2048, DM = 768, NH_ = 12, F_ = 16, DH_ = 64;
constexpr int NPROJ = 1152;
constexpr int CH = 64, NCH = L_ / CH;  // scan chunking (64-row chunks)

typedef __bf16 bf16x8 __attribute__((ext_vector_type(8)));
typedef __bf16 bf16x4 __attribute__((ext_vector_type(4)));
typedef float f32x4 __attribute__((ext_vector_type(4)));
typedef float f32x16 __attribute__((ext_vector_type(16)));
typedef unsigned u32x2 __attribute__((ext_vector_type(2)));

#define GLOAD16(g, l)                                                        \
  __builtin_amdgcn_global_load_lds(                                          \
      (const __attribute__((address_space(1))) void*)(g),                    \
      (__attribute__((address_space(3))) void*)(l), 16, 0, 0)

__device__ __forceinline__ unsigned cvt_pk_bf16(float lo, float hi) {
  unsigned r;
  asm("v_cvt_pk_bf16_f32 %0, %1, %2" : "=v"(r) : "v"(lo), "v"(hi));
  return r;
}

union pa_u { unsigned u[4]; bf16x8 v; };

// pack 16 f32 P-slices -> two PV A-fragments via cvt_pk + permlane32_swap
__device__ __forceinline__ void pack_p(const f32x16& s, pa_u& pa0, pa_u& pa1) {
  unsigned w0 = cvt_pk_bf16(s[0], s[1]),   w1 = cvt_pk_bf16(s[2], s[3]);
  unsigned w2 = cvt_pk_bf16(s[4], s[5]),   w3 = cvt_pk_bf16(s[6], s[7]);
  unsigned w4 = cvt_pk_bf16(s[8], s[9]),   w5 = cvt_pk_bf16(s[10], s[11]);
  unsigned w6 = cvt_pk_bf16(s[12], s[13]), w7 = cvt_pk_bf16(s[14], s[15]);
  u32x2 r0 = __builtin_amdgcn_permlane32_swap(w0, w2, false, false);
  u32x2 r1 = __builtin_amdgcn_permlane32_swap(w1, w3, false, false);
  u32x2 r2 = __builtin_amdgcn_permlane32_swap(w4, w6, false, false);
  u32x2 r3 = __builtin_amdgcn_permlane32_swap(w5, w7, false, false);
  pa0.u[0] = r0[0]; pa0.u[1] = r1[0]; pa0.u[2] = r0[1]; pa0.u[3] = r1[1];
  pa1.u[0] = r2[0]; pa1.u[1] = r3[0]; pa1.u[2] = r2[1]; pa1.u[3] = r3[1];
}

// ---------------- prep: LDS-tiled weight transposes + hs cast ------------
// blocks [0,1440): 32x32 f32 transpose tiles -> bf16 (Wq/Wk/Wv -> WqkvT, Wo -> WoT)
// blocks [1440,2976): hs f32 -> bf16 cast, 2048 elems/block
__global__ __launch_bounds__(256)
void prep_kernel(const float* __restrict__ hs, const float* __restrict__ Wq,
                 const float* __restrict__ Wk, const float* __restrict__ Wv,
                 const float* __restrict__ Wo, __bf16* __restrict__ hsb,
                 __bf16* __restrict__ WqkvT, __bf16* __restrict__ WoT) {
  int bx = blockIdx.x;
  if (bx < 1440) {
    const float* src; __bf16* dst; int C, kt, nt;
    int id = bx;
    if (id < 144)      { src = Wq; dst = WqkvT;             C = 192; kt = id / 6;  nt = id % 6;  }
    else if (id < 288) { id -= 144; src = Wk; dst = WqkvT + (size_t)192 * 768; C = 192; kt = id / 6;  nt = id % 6;  }
    else if (id < 864) { id -= 288; src = Wv; dst = WqkvT + (size_t)384 * 768; C = 768; kt = id / 24; nt = id % 24; }
    else               { id -= 864; src = Wo; dst = WoT;    C = 768; kt = id / 24; nt = id % 24; }
    __shared__ float ld[32][33];
    int tid = threadIdx.x;
    int r = tid >> 3, cg = tid & 7;
    int k0 = kt * 32, n0 = nt * 32;
    float4 v = *(const float4*)(src + (size_t)(k0 + r) * C + n0 + cg * 4);
    ld[r][cg * 4 + 0] = v.x;
    ld[r][cg * 4 + 1] = v.y;
    ld[r][cg * 4 + 2] = v.z;
    ld[r][cg * 4 + 3] = v.w;
    __syncthreads();
    int nl = tid >> 3, kg = tid & 7;
    bf16x4 o;
#pragma unroll
    for (int j = 0; j < 4; j++) o[j] = (__bf16)ld[kg * 4 + j][nl];
    *(bf16x4*)(dst + (size_t)(n0 + nl) * 768 + k0 + kg * 4) = o;
  } else {
    int base = (bx - 1440) * 2048 + threadIdx.x * 8;
    float4 a = *(const float4*)(hs + base);
    float4 b4 = *(const float4*)(hs + base + 4);
    bf16x8 o;
    o[0] = (__bf16)a.x;  o[1] = (__bf16)a.y;  o[2] = (__bf16)a.z;  o[3] = (__bf16)a.w;
    o[4] = (__bf16)b4.x; o[5] = (__bf16)b4.y; o[6] = (__bf16)b4.z; o[7] = (__bf16)b4.w;
    *(bf16x8*)(hsb + base) = o;
  }
}

// ---------------- bf16 MFMA GEMM: C(MxN) = A(MxK) @ Bt(NxK)^T ------------
// mode 1 (projection pass): q-columns (n<192) go bf16 to Qh, and the
// epilogue reduces per-64-row-chunk column sums of k/v columns into csum.
__global__ __launch_bounds__(256)
void gemm_bf16(const __bf16* __restrict__ A, const __bf16* __restrict__ Bt,
               int M, int N, int K, float* __restrict__ C,
               __bf16* __restrict__ Qh, float* __restrict__ csum, int mode) {
  __shared__ __align__(16) __bf16 Al[128 * 32];
  __shared__ __align__(16) __bf16 Bl[128 * 32];
  __shared__ float csl[2][128];
  int tid = threadIdx.x;
  int m0 = blockIdx.y * 128, n0 = blockIdx.x * 128;
  int w = tid >> 6, l = tid & 63, lr = l & 15, lg = l >> 4;
  int wr = w >> 1, wc = w & 1;
  f32x4 acc[4][4] = {};
  const __bf16* Ab = A + (size_t)m0 * K;
  const __bf16* Bb = Bt + (size_t)n0 * K;
  for (int k0 = 0; k0 < K; k0 += 32) {
    __syncthreads();
#pragma unroll
    for (int i = 0; i < 2; i++) {
      int idx = i * 256 + tid;
      int row = idx >> 2, ch = idx & 3;
      GLOAD16(Ab + (size_t)row * K + k0 + ch * 8, &Al[idx * 8]);
    }
#pragma unroll
    for (int i = 0; i < 2; i++) {
      int idx = i * 256 + tid;
      int row = idx >> 2, ch = idx & 3;
      GLOAD16(Bb + (size_t)row * K + k0 + ch * 8, &Bl[idx * 8]);
    }
    asm volatile("s_waitcnt vmcnt(0)" ::: "memory");
    __syncthreads();
    bf16x8 af[4], bfr[4];
#pragma unroll
    for (int mi = 0; mi < 4; mi++)
      af[mi] = *(const bf16x8*)&Al[(wr * 64 + mi * 16 + lr) * 32 + lg * 8];
#pragma unroll
    for (int ni = 0; ni < 4; ni++)
      bfr[ni] = *(const bf16x8*)&Bl[(wc * 64 + ni * 16 + lr) * 32 + lg * 8];
#pragma unroll
    for (int mi = 0; mi < 4; mi++)
#pragma unroll
      for (int ni = 0; ni < 4; ni++)
        acc[mi][ni] = __builtin_amdgcn_mfma_f32_16x16x32_bf16(
            af[mi], bfr[ni], acc[mi][ni], 0, 0, 0);
  }
#pragma unroll
  for (int mi = 0; mi < 4; mi++)
#pragma unroll
    for (int ni = 0; ni < 4; ni++) {
      int n = n0 + wc * 64 + ni * 16 + lr;
#pragma unroll
      for (int r = 0; r < 4; r++) {
        int m = m0 + wr * 64 + mi * 16 + lg * 4 + r;
        float v = acc[mi][ni][r];
        if (mode == 1 && n < 192) {
          int h = n >> 4, f = n & 15;
          int b = m >> 11, ll = m & 2047;
          Qh[((size_t)(b * NH_ + h) * L_ + ll) * F_ + f] = (__bf16)v;
        } else {
          C[(size_t)m * N + n] = v;
        }
      }
    }
  if (mode == 1) {
#pragma unroll
    for (int ni = 0; ni < 4; ni++) {
      float cs = 0.f;
#pragma unroll
      for (int mi = 0; mi < 4; mi++)
#pragma unroll
        for (int r = 0; r < 4; r++) cs += acc[mi][ni][r];
      cs += __shfl_xor(cs, 16, 64);
      cs += __shfl_xor(cs, 32, 64);
      if (lg == 0) csl[wr][wc * 64 + ni * 16 + lr] = cs;
    }
    __syncthreads();
    int colg = tid & 127, half = tid >> 7;
    int n = n0 + colg;
    if (n >= 192) {
      int b = m0 >> 11;
      int ch64 = ((m0 & 2047) >> 6) + half;
      float v = csl[half][colg];
      int h, c;
      if (n < 384) { h = (n - 192) >> 4; c = (n - 192) & 15; }
      else         { h = (n - 384) >> 6; c = 16 + ((n - 384) & 63); }
      csum[((size_t)(b * NH_ + h) * NCH + ch64) * 80 + c] = v;
    }
  }
}

// ---------------- apply: prefix base + in-chunk mean scan ----------------
// CVf fragment-native layout: element (d, p) at [bh][p>>4][d][p&15].
__global__ __launch_bounds__(128)
void scan_apply(const float* __restrict__ proj, const float* __restrict__ csum,
                __bf16* __restrict__ CKh, __bf16* __restrict__ CVf,
                __bf16* __restrict__ Yb) {
  int bh = blockIdx.y, ch = blockIdx.x;
  int b = bh / NH_, h = bh % NH_;
  int c = threadIdx.x;
  if (c >= 80) return;
  int off = (c < 16) ? (192 + h * 16 + c) : (384 + h * 64 + (c - 16));
  const float* src = proj + ((size_t)b * L_ + ch * CH) * NPROJ + off;
  float run = 0.f;
  for (int j = 0; j < ch; j++) run += csum[((size_t)bh * NCH + j) * 80 + c];
  if (c < 16) {
    __bf16* ckp = CKh + ((size_t)bh * L_ + ch * CH) * F_ + c;
    for (int r = 0; r < CH; r++) {
      float val = src[(size_t)r * NPROJ];
      run += val;
      float mean = run / (float)(ch * CH + r + 1);
      ckp[(size_t)r * F_] = (__bf16)(val - mean);
    }
  } else {
    int d = c - 16;
    __bf16* cvbase = CVf + (size_t)bh * 128 * 1024;  // 128 chunks x 64 d x 16
    __bf16* yp = Yb + ((size_t)(b * L_ + ch * CH)) * DM + h * DH_ + d;
    for (int r = 0; r < CH; r++) {
      float val = src[(size_t)r * NPROJ];
      run += val;
      int p = ch * CH + r;
      float mean = run / (float)(p + 1);
      cvbase[(size_t)(p >> 4) * 1024 + d * 16 + (p & 15)] = (__bf16)(val - mean);
      yp[(size_t)r * DM] = (__bf16)mean;
    }
  }
}

// ---------------- attention: QBLK=64, KV-split waves, in-register P ------
// block = (bh, 64 q-rows). Wave w handles p-tiles w, w+4, ... for BOTH
// 32-row q-subtiles; ka/bv loads shared between subtiles (halves traffic).
__global__ __launch_bounds__(256)
void attn_mfma(const __bf16* __restrict__ Qh, const __bf16* __restrict__ CKh,
               const __bf16* __restrict__ CVf, __bf16* __restrict__ qkv,
               float* __restrict__ rs2) {
  __shared__ float slab[4][32][65];
  __shared__ float s2slab[4][64];
  int bh = blockIdx.y;
  int qi = (gridDim.x - 1) - blockIdx.x;  // big tiles first
  int q0 = qi * 64;
  int qt0 = 2 * qi, qt1 = 2 * qi + 1;
  int tid = threadIdx.x;
  int w = tid >> 6, l = tid & 63;
  int lp = l & 31, hi = l >> 5;

  bf16x8 qb0 = *(const bf16x8*)(Qh + ((size_t)bh * L_ + q0 + lp) * F_ + hi * 8);
  bf16x8 qb1 = *(const bf16x8*)(Qh + ((size_t)bh * L_ + q0 + 32 + lp) * F_ + hi * 8);
  const __bf16* ckb = CKh + (size_t)bh * L_ * F_;
  const __bf16* cvb = CVf + (size_t)bh * 128 * 1024;

  f32x16 pv00 = {}, pv01 = {}, pv10 = {}, pv11 = {};
  float s2q0 = 0.f, s2q1 = 0.f;

  for (int pt = w; pt <= qt1; pt += 4) {
    bf16x8 ka = *(const bf16x8*)(ckb + (size_t)(pt * 32 + lp) * F_ + hi * 8);
    const __bf16* cvp = cvb + (size_t)(2 * pt) * 1024 + lp * 16 + hi * 8;
    bf16x8 bv0 = *(const bf16x8*)(cvp);
    bf16x8 bv1 = *(const bf16x8*)(cvp + 512);
    bf16x8 bv2 = *(const bf16x8*)(cvp + 1024);
    bf16x8 bv3 = *(const bf16x8*)(cvp + 1536);
    f32x16 s1 = {};
    s1 = __builtin_amdgcn_mfma_f32_32x32x16_bf16(ka, qb1, s1, 0, 0, 0);
    if (pt <= qt0) {
      f32x16 s0 = {};
      s0 = __builtin_amdgcn_mfma_f32_32x32x16_bf16(ka, qb0, s0, 0, 0, 0);
      if (pt == qt0) {
#pragma unroll
        for (int reg = 0; reg < 16; reg++) {
          int pidx = (reg & 3) + 8 * (reg >> 2) + 4 * hi;
          if (pidx > lp) s0[reg] = 0.f;
        }
      }
#pragma unroll
      for (int reg = 0; reg < 16; reg++) s2q0 = fmaf(s0[reg], s0[reg], s2q0);
      pa_u pa0, pa1;
      pack_p(s0, pa0, pa1);
      pv00 = __builtin_amdgcn_mfma_f32_32x32x16_bf16(pa0.v, bv0, pv00, 0, 0, 0);
      pv01 = __builtin_amdgcn_mfma_f32_32x32x16_bf16(pa0.v, bv1, pv01, 0, 0, 0);
      pv00 = __builtin_amdgcn_mfma_f32_32x32x16_bf16(pa1.v, bv2, pv00, 0, 0, 0);
      pv01 = __builtin_amdgcn_mfma_f32_32x32x16_bf16(pa1.v, bv3, pv01, 0, 0, 0);
    }
    if (pt == qt1) {
#pragma unroll
      for (int reg = 0; reg < 16; reg++) {
        int pidx = (reg & 3) + 8 * (reg >> 2) + 4 * hi;
        if (pidx > lp) s1[reg] = 0.f;
      }
    }
#pragma unroll
    for (int reg = 0; reg < 16; reg++) s2q1 = fmaf(s1[reg], s1[reg], s2q1);
    pa_u pb0, pb1;
    pack_p(s1, pb0, pb1);
    pv10 = __builtin_amdgcn_mfma_f32_32x32x16_bf16(pb0.v, bv0, pv10, 0, 0, 0);
    pv11 = __builtin_amdgcn_mfma_f32_32x32x16_bf16(pb0.v, bv1, pv11, 0, 0, 0);
    pv10 = __builtin_amdgcn_mfma_f32_32x32x16_bf16(pb1.v, bv2, pv10, 0, 0, 0);
    pv11 = __builtin_amdgcn_mfma_f32_32x32x16_bf16(pb1.v, bv3, pv11, 0, 0, 0);
  }

  // s2: merge hi-halves (each covered half the p-rows of its tiles)
  s2q0 += __shfl_xor(s2q0, 32, 64);
  s2q1 += __shfl_xor(s2q1, 32, 64);
  if (hi == 0) {
    s2slab[w][lp] = s2q0;
    s2slab[w][32 + lp] = s2q1;
  }
  // phase A: q-subtile 0
#pragma unroll
  for (int reg = 0; reg < 16; reg++) {
    int ql = (reg & 3) + 8 * (reg >> 2) + 4 * hi;
    slab[w][ql][lp] = pv00[reg];
    slab[w][ql][32 + lp] = pv01[reg];
  }
  __syncthreads();
  if (tid < 64) {
    float v = s2slab[0][tid] + s2slab[1][tid] + s2slab[2][tid] + s2slab[3][tid];
    rs2[(size_t)bh * L_ + q0 + tid] = v * (1.0f / 128.0f);
  }
  {
    int q = tid >> 3, seg = tid & 7;
    bf16x8 o;
#pragma unroll
    for (int j = 0; j < 8; j++) {
      int d = seg * 8 + j;
      float acc = slab[0][q][d] + slab[1][q][d] + slab[2][q][d] + slab[3][q][d];
      o[j] = (__bf16)(acc * 0.125f);
    }
    *(bf16x8*)(qkv + ((size_t)bh * L_ + q0 + q) * DH_ + seg * 8) = o;
  }
  __syncthreads();
  // phase B: q-subtile 1
#pragma unroll
  for (int reg = 0; reg < 16; reg++) {
    int ql = (reg & 3) + 8 * (reg >> 2) + 4 * hi;
    slab[w][ql][lp] = pv10[reg];
    slab[w][ql][32 + lp] = pv11[reg];
  }
  __syncthreads();
  {
    int q = tid >> 3, seg = tid & 7;
    bf16x8 o;
#pragma unroll
    for (int j = 0; j < 8; j++) {
      int d = seg * 8 + j;
      float acc = slab[0][q][d] + slab[1][q][d] + slab[2][q][d] + slab[3][q][d];
      o[j] = (__bf16)(acc * 0.125f);
    }
    *(bf16x8*)(qkv + ((size_t)bh * L_ + q0 + 32 + q) * DH_ + seg * 8) = o;
  }
}

// ---------------- combine (denominator scan fused): Yb += qkv/denom ------
__global__ __launch_bounds__(256)
void combine_kernel(const __bf16* __restrict__ qkv, const float* __restrict__ rs2,
                    __bf16* __restrict__ Yb) {
  int bh = blockIdx.y, lt = blockIdx.x;
  int b = bh / NH_, h = bh % NH_;
  int t = threadIdx.x;
  int l0 = lt * 256;
  __shared__ float part[256];
  __shared__ float dinv[256];
  const float* rs = rs2 + (size_t)bh * L_;
  float vals[8];
  float run = 0.f;
#pragma unroll
  for (int i = 0; i < 8; i++) { run += rs[t * 8 + i]; vals[i] = run; }
  part[t] = run;
  __syncthreads();
  for (int o = 1; o < 256; o <<= 1) {
    float add = (t >= o) ? part[t - o] : 0.f;
    __syncthreads();
    part[t] += add;
    __syncthreads();
  }
  float base = (t > 0) ? part[t - 1] : 0.f;
#pragma unroll
  for (int i = 0; i < 8; i++) {
    int ll = t * 8 + i;
    if (ll >= l0 && ll < l0 + 256)
      dinv[ll - l0] = 1.0f / ((float)(ll + 1) + base + vals[i]);
  }
  __syncthreads();
#pragma unroll
  for (int it = 0; it < 8; it++) {
    int v = it * 256 + t;
    int ll = v >> 3, d8 = v & 7;
    bf16x8 q8 = *(const bf16x8*)(qkv + ((size_t)bh * L_ + l0 + ll) * DH_ + d8 * 8);
    __bf16* yp = Yb + ((size_t)(b * L_ + l0 + ll)) * DM + h * DH_ + d8 * 8;
    bf16x8 y8 = *(const bf16x8*)yp;
    float iv = dinv[ll];
#pragma unroll
    for (int j = 0; j < 8; j++)
      y8[j] = (__bf16)((float)y8[j] + (float)q8[j] * iv);
    *(bf16x8*)yp = y8;
  }
}

extern "C" void kernel_launch(void* const* d_in, const int* in_sizes, int n_in,
                              void* d_out, int out_size, void* d_ws, size_t ws_size,
                              hipStream_t stream) {
  const float* hs = (const float*)d_in[0];
  const float* Wq = (const float*)d_in[1];
  const float* Wk = (const float*)d_in[2];
  const float* Wv = (const float*)d_in[3];
  const float* Wo = (const float*)d_in[4];
  float* out = (float*)d_out;
  char* w = (char*)d_ws;

  __bf16* hsb   = (__bf16*)(w);                      // 6,291,456
  __bf16* WqkvT = (__bf16*)(w + 6291456);            // 1,769,472
  __bf16* WoT   = (__bf16*)(w + 8060928);            // 1,179,648
  float*  proj  = (float*)(w + 9240576);             // 18,874,368
  __bf16* qkvb  = (__bf16*)(w + 28114944);           // 6,291,456
  __bf16* Qh    = (__bf16*)(w + 34406400);           // 1,572,864
  __bf16* CKh   = (__bf16*)(w + 35979264);           // 1,572,864
  __bf16* CVfg  = (__bf16*)(w + 37552128);           // 6,291,456
  __bf16* Yb    = (__bf16*)(w + 43843584);           // 6,291,456
  float*  rs2   = (float*)(w + 50135040);            // 98,304
  float*  csum  = (float*)(w + 50331648);            // 245,760

  prep_kernel<<<2976, 256, 0, stream>>>(hs, Wq, Wk, Wv, Wo, hsb, WqkvT, WoT);
  dim3 g1(NPROJ / 128, (B_ * L_) / 128);
  gemm_bf16<<<g1, 256, 0, stream>>>(hsb, WqkvT, B_ * L_, NPROJ, DM, proj, Qh, csum, 1);
  dim3 gs(NCH, B_ * NH_);
  scan_apply<<<gs, 128, 0, stream>>>(proj, csum, CKh, CVfg, Yb);
  dim3 g3(L_ / 64, 24);
  attn_mfma<<<g3, 256, 0, stream>>>(Qh, CKh, CVfg, qkvb, rs2);
  dim3 g5(8, 24);
  combine_kernel<<<g5, 256, 0, stream>>>(qkvb, rs2, Yb);
  dim3 g6(DM / 128, (B_ * L_) / 128);
  gemm_bf16<<<g6, 256, 0, stream>>>(Yb, WoT, B_ * L_, DM, DM, out, nullptr, nullptr, 0);
}

// Round 10
// 119.790 us; speedup vs baseline: 1.4802x; 1.1040x over previous
//
#include <hip/hip_runtime.h>
#include <hip/hip_bf16.h>
#include <stdint.h>

constexpr int B_ = 2, L_ = 2048, DM = 768, NH_ = 12, F_ = 16, DH_ = 64;
constexpr int CH = 64, NCH = L_ / CH;  // scan chunking (64-row chunks)

typedef __bf16 bf16x8 __attribute__((ext_vector_type(8)));
typedef __bf16 bf16x4 __attribute__((ext_vector_type(4)));
typedef float f32x4 __attribute__((ext_vector_type(4)));
typedef float f32x16 __attribute__((ext_vector_type(16)));
typedef unsigned u32x2 __attribute__((ext_vector_type(2)));

#define GLOAD16(g, l)                                                        \
  __builtin_amdgcn_global_load_lds(                                          \
      (const __attribute__((address_space(1))) void*)(g),                    \
      (__attribute__((address_space(3))) void*)(l), 16, 0, 0)

__device__ __forceinline__ unsigned cvt_pk_bf16(float lo, float hi) {
  unsigned r;
  asm("v_cvt_pk_bf16_f32 %0, %1, %2" : "=v"(r) : "v"(lo), "v"(hi));
  return r;
}

union pa_u { unsigned u[4]; bf16x8 v; };

__device__ __forceinline__ void pack_p(const f32x16& s, pa_u& pa0, pa_u& pa1) {
  unsigned w0 = cvt_pk_bf16(s[0], s[1]),   w1 = cvt_pk_bf16(s[2], s[3]);
  unsigned w2 = cvt_pk_bf16(s[4], s[5]),   w3 = cvt_pk_bf16(s[6], s[7]);
  unsigned w4 = cvt_pk_bf16(s[8], s[9]),   w5 = cvt_pk_bf16(s[10], s[11]);
  unsigned w6 = cvt_pk_bf16(s[12], s[13]), w7 = cvt_pk_bf16(s[14], s[15]);
  u32x2 r0 = __builtin_amdgcn_permlane32_swap(w0, w2, false, false);
  u32x2 r1 = __builtin_amdgcn_permlane32_swap(w1, w3, false, false);
  u32x2 r2 = __builtin_amdgcn_permlane32_swap(w4, w6, false, false);
  u32x2 r3 = __builtin_amdgcn_permlane32_swap(w5, w7, false, false);
  pa0.u[0] = r0[0]; pa0.u[1] = r1[0]; pa0.u[2] = r0[1]; pa0.u[3] = r1[1];
  pa1.u[0] = r2[0]; pa1.u[1] = r3[0]; pa1.u[2] = r2[1]; pa1.u[3] = r3[1];
}

// ---------------- prep: LDS-tiled weight transposes + hs cast ------------
__global__ __launch_bounds__(256)
void prep_kernel(const float* __restrict__ hs, const float* __restrict__ Wq,
                 const float* __restrict__ Wk, const float* __restrict__ Wv,
                 const float* __restrict__ Wo, __bf16* __restrict__ hsb,
                 __bf16* __restrict__ WqkvT, __bf16* __restrict__ WoT) {
  int bx = blockIdx.x;
  if (bx < 1440) {
    const float* src; __bf16* dst; int C, kt, nt;
    int id = bx;
    if (id < 144)      { src = Wq; dst = WqkvT;             C = 192; kt = id / 6;  nt = id % 6;  }
    else if (id < 288) { id -= 144; src = Wk; dst = WqkvT + (size_t)192 * 768; C = 192; kt = id / 6;  nt = id % 6;  }
    else if (id < 864) { id -= 288; src = Wv; dst = WqkvT + (size_t)384 * 768; C = 768; kt = id / 24; nt = id % 24; }
    else               { id -= 864; src = Wo; dst = WoT;    C = 768; kt = id / 24; nt = id % 24; }
    __shared__ float ld[32][33];
    int tid = threadIdx.x;
    int r = tid >> 3, cg = tid & 7;
    int k0 = kt * 32, n0 = nt * 32;
    float4 v = *(const float4*)(src + (size_t)(k0 + r) * C + n0 + cg * 4);
    ld[r][cg * 4 + 0] = v.x;
    ld[r][cg * 4 + 1] = v.y;
    ld[r][cg * 4 + 2] = v.z;
    ld[r][cg * 4 + 3] = v.w;
    __syncthreads();
    int nl = tid >> 3, kg = tid & 7;
    bf16x4 o;
#pragma unroll
    for (int j = 0; j < 4; j++) o[j] = (__bf16)ld[kg * 4 + j][nl];
    *(bf16x4*)(dst + (size_t)(n0 + nl) * 768 + k0 + kg * 4) = o;
  } else {
    int base = (bx - 1440) * 2048 + threadIdx.x * 8;
    float4 a = *(const float4*)(hs + base);
    float4 b4 = *(const float4*)(hs + base + 4);
    bf16x8 o;
    o[0] = (__bf16)a.x;  o[1] = (__bf16)a.y;  o[2] = (__bf16)a.z;  o[3] = (__bf16)a.w;
    o[4] = (__bf16)b4.x; o[5] = (__bf16)b4.y; o[6] = (__bf16)b4.z; o[7] = (__bf16)b4.w;
    *(bf16x8*)(hsb + base) = o;
  }
}

// ---------------- bf16 MFMA GEMM, 2-phase double-buffered ----------------
// C(MxN) = A(MxK) @ Bt(NxK)^T.  BM=128, BK=32.
// MODE 1 (BN=128): projection pass -> Qh/Kh/Vh bf16 per-head + csum.
// MODE 0: plain fp32 C output.
template<int BN, int MODE>
__global__ __launch_bounds__(256)
void gemm_bf16(const __bf16* __restrict__ A, const __bf16* __restrict__ Bt,
               int M, int N, int K, float* __restrict__ C,
               __bf16* __restrict__ Qh, __bf16* __restrict__ Kh,
               __bf16* __restrict__ Vh, float* __restrict__ csum) {
  __shared__ __align__(16) __bf16 Al[2][128 * 32];
  __shared__ __align__(16) __bf16 Bl[2][BN * 32];
  __shared__ float csl[2][128];
  int tid = threadIdx.x;
  int m0 = blockIdx.y * 128, n0 = blockIdx.x * BN;
  int w = tid >> 6, l = tid & 63, lr = l & 15, lg = l >> 4;
  constexpr int MI = (BN == 128) ? 4 : 2;
  int rowb = (BN == 128) ? (w >> 1) * 64 : w * 32;
  int colb = (BN == 128) ? (w & 1) * 64 : 0;
  f32x4 acc[MI][4] = {};
  const __bf16* Ab = A + (size_t)m0 * K;
  const __bf16* Bb = Bt + (size_t)n0 * K;
  int nt = K / 32;

  auto stage = [&](int buf, int k0) {
#pragma unroll
    for (int i = 0; i < 2; i++) {
      int idx = i * 256 + tid;
      GLOAD16(Ab + (size_t)(idx >> 2) * K + k0 + (idx & 3) * 8, &Al[buf][idx * 8]);
    }
    if constexpr (BN == 128) {
#pragma unroll
      for (int i = 0; i < 2; i++) {
        int idx = i * 256 + tid;
        GLOAD16(Bb + (size_t)(idx >> 2) * K + k0 + (idx & 3) * 8, &Bl[buf][idx * 8]);
      }
    } else {
      GLOAD16(Bb + (size_t)(tid >> 2) * K + k0 + (tid & 3) * 8, &Bl[buf][tid * 8]);
    }
  };

  stage(0, 0);
  asm volatile("s_waitcnt vmcnt(0)" ::: "memory");
  __syncthreads();
  int cur = 0;
  for (int t = 0; t < nt; t++) {
    if (t + 1 < nt) stage(cur ^ 1, (t + 1) * 32);  // issue next tile early
    bf16x8 af[MI], bfr[4];
#pragma unroll
    for (int mi = 0; mi < MI; mi++)
      af[mi] = *(const bf16x8*)&Al[cur][(rowb + mi * 16 + lr) * 32 + lg * 8];
#pragma unroll
    for (int ni = 0; ni < 4; ni++)
      bfr[ni] = *(const bf16x8*)&Bl[cur][(colb + ni * 16 + lr) * 32 + lg * 8];
#pragma unroll
    for (int mi = 0; mi < MI; mi++)
#pragma unroll
      for (int ni = 0; ni < 4; ni++)
        acc[mi][ni] = __builtin_amdgcn_mfma_f32_16x16x32_bf16(
            af[mi], bfr[ni], acc[mi][ni], 0, 0, 0);
    asm volatile("s_waitcnt vmcnt(0)" ::: "memory");  // next buffer landed
    __syncthreads();
    cur ^= 1;
  }

#pragma unroll
  for (int mi = 0; mi < MI; mi++)
#pragma unroll
    for (int ni = 0; ni < 4; ni++) {
      int n = n0 + colb + ni * 16 + lr;
#pragma unroll
      for (int r = 0; r < 4; r++) {
        int m = m0 + rowb + mi * 16 + lg * 4 + r;
        float v = acc[mi][ni][r];
        if constexpr (MODE == 1) {
          int b = m >> 11, ll = m & 2047;
          if (n < 192)
            Qh[((size_t)(b * NH_ + (n >> 4)) * L_ + ll) * F_ + (n & 15)] = (__bf16)v;
          else if (n < 384)
            Kh[((size_t)(b * NH_ + ((n - 192) >> 4)) * L_ + ll) * F_ + ((n - 192) & 15)] = (__bf16)v;
          else
            Vh[((size_t)(b * NH_ + ((n - 384) >> 6)) * L_ + ll) * DH_ + ((n - 384) & 63)] = (__bf16)v;
        } else {
          C[(size_t)m * N + n] = v;
        }
      }
    }
  if constexpr (MODE == 1) {
    // per-64-row-chunk column sums from the SAME bf16-rounded values
#pragma unroll
    for (int ni = 0; ni < 4; ni++) {
      float cs = 0.f;
#pragma unroll
      for (int mi = 0; mi < MI; mi++)
#pragma unroll
        for (int r = 0; r < 4; r++) cs += (float)(__bf16)acc[mi][ni][r];
      cs += __shfl_xor(cs, 16, 64);
      cs += __shfl_xor(cs, 32, 64);
      if (lg == 0) csl[w >> 1][(w & 1) * 64 + ni * 16 + lr] = cs;
    }
    __syncthreads();
    int colg = tid & 127, half = tid >> 7;
    int n = n0 + colg;
    if (n >= 192) {
      int b = m0 >> 11;
      int ch64 = ((m0 & 2047) >> 6) + half;
      float v = csl[half][colg];
      int h, c;
      if (n < 384) { h = (n - 192) >> 4; c = (n - 192) & 15; }
      else         { h = (n - 384) >> 6; c = 16 + ((n - 384) & 63); }
      csum[((size_t)(b * NH_ + h) * NCH + ch64) * 80 + c] = v;
    }
  }
}

// ---------------- apply: prefix base + in-chunk mean scan (bf16 in) ------
// CVf fragment-native layout: element (d, p) at [bh][p>>4][d][p&15].
__global__ __launch_bounds__(128)
void scan_apply(const __bf16* __restrict__ Kh, const __bf16* __restrict__ Vh,
                const float* __restrict__ csum,
                __bf16* __restrict__ CKh, __bf16* __restrict__ CVf,
                __bf16* __restrict__ Yb) {
  int bh = blockIdx.y, ch = blockIdx.x;
  int b = bh / NH_, h = bh % NH_;
  int c = threadIdx.x;
  if (c >= 80) return;
  float run = 0.f;
  for (int j = 0; j < ch; j++) run += csum[((size_t)bh * NCH + j) * 80 + c];
  if (c < 16) {
    const __bf16* src = Kh + ((size_t)bh * L_ + ch * CH) * F_ + c;
    __bf16* ckp = CKh + ((size_t)bh * L_ + ch * CH) * F_ + c;
    for (int r = 0; r < CH; r++) {
      float val = (float)src[(size_t)r * F_];
      run += val;
      float mean = run / (float)(ch * CH + r + 1);
      ckp[(size_t)r * F_] = (__bf16)(val - mean);
    }
  } else {
    int d = c - 16;
    const __bf16* src = Vh + ((size_t)bh * L_ + ch * CH) * DH_ + d;
    __bf16* cvbase = CVf + (size_t)bh * 128 * 1024;
    __bf16* yp = Yb + ((size_t)(b * L_ + ch * CH)) * DM + h * DH_ + d;
    for (int r = 0; r < CH; r++) {
      float val = (float)src[(size_t)r * DH_];
      run += val;
      int p = ch * CH + r;
      float mean = run / (float)(p + 1);
      cvbase[(size_t)(p >> 4) * 1024 + d * 16 + (p & 15)] = (__bf16)(val - mean);
      yp[(size_t)r * DM] = (__bf16)mean;
    }
  }
}

// ---------------- attention: QBLK=64, KV-split waves, in-register P ------
__global__ __launch_bounds__(256)
void attn_mfma(const __bf16* __restrict__ Qh, const __bf16* __restrict__ CKh,
               const __bf16* __restrict__ CVf, __bf16* __restrict__ qkv,
               float* __restrict__ rs2) {
  __shared__ float slab[4][32][65];
  __shared__ float s2slab[4][64];
  int bh = blockIdx.y;
  int qi = (gridDim.x - 1) - blockIdx.x;  // big tiles first
  int q0 = qi * 64;
  int qt0 = 2 * qi, qt1 = 2 * qi + 1;
  int tid = threadIdx.x;
  int w = tid >> 6, l = tid & 63;
  int lp = l & 31, hi = l >> 5;

  bf16x8 qb0 = *(const bf16x8*)(Qh + ((size_t)bh * L_ + q0 + lp) * F_ + hi * 8);
  bf16x8 qb1 = *(const bf16x8*)(Qh + ((size_t)bh * L_ + q0 + 32 + lp) * F_ + hi * 8);
  const __bf16* ckb = CKh + (size_t)bh * L_ * F_;
  const __bf16* cvb = CVf + (size_t)bh * 128 * 1024;

  f32x16 pv00 = {}, pv01 = {}, pv10 = {}, pv11 = {};
  float s2q0 = 0.f, s2q1 = 0.f;

  for (int pt = w; pt <= qt1; pt += 4) {
    bf16x8 ka = *(const bf16x8*)(ckb + (size_t)(pt * 32 + lp) * F_ + hi * 8);
    const __bf16* cvp = cvb + (size_t)(2 * pt) * 1024 + lp * 16 + hi * 8;
    bf16x8 bv0 = *(const bf16x8*)(cvp);
    bf16x8 bv1 = *(const bf16x8*)(cvp + 512);
    bf16x8 bv2 = *(const bf16x8*)(cvp + 1024);
    bf16x8 bv3 = *(const bf16x8*)(cvp + 1536);
    f32x16 s1 = {};
    s1 = __builtin_amdgcn_mfma_f32_32x32x16_bf16(ka, qb1, s1, 0, 0, 0);
    if (pt <= qt0) {
      f32x16 s0 = {};
      s0 = __builtin_amdgcn_mfma_f32_32x32x16_bf16(ka, qb0, s0, 0, 0, 0);
      if (pt == qt0) {
#pragma unroll
        for (int reg = 0; reg < 16; reg++) {
          int pidx = (reg & 3) + 8 * (reg >> 2) + 4 * hi;
          if (pidx > lp) s0[reg] = 0.f;
        }
      }
#pragma unroll
      for (int reg = 0; reg < 16; reg++) s2q0 = fmaf(s0[reg], s0[reg], s2q0);
      pa_u pa0, pa1;
      pack_p(s0, pa0, pa1);
      pv00 = __builtin_amdgcn_mfma_f32_32x32x16_bf16(pa0.v, bv0, pv00, 0, 0, 0);
      pv01 = __builtin_amdgcn_mfma_f32_32x32x16_bf16(pa0.v, bv1, pv01, 0, 0, 0);
      pv00 = __builtin_amdgcn_mfma_f32_32x32x16_bf16(pa1.v, bv2, pv00, 0, 0, 0);
      pv01 = __builtin_amdgcn_mfma_f32_32x32x16_bf16(pa1.v, bv3, pv01, 0, 0, 0);
    }
    if (pt == qt1) {
#pragma unroll
      for (int reg = 0; reg < 16; reg++) {
        int pidx = (reg & 3) + 8 * (reg >> 2) + 4 * hi;
        if (pidx > lp) s1[reg] = 0.f;
      }
    }
#pragma unroll
    for (int reg = 0; reg < 16; reg++) s2q1 = fmaf(s1[reg], s1[reg], s2q1);
    pa_u pb0, pb1;
    pack_p(s1, pb0, pb1);
    pv10 = __builtin_amdgcn_mfma_f32_32x32x16_bf16(pb0.v, bv0, pv10, 0, 0, 0);
    pv11 = __builtin_amdgcn_mfma_f32_32x32x16_bf16(pb0.v, bv1, pv11, 0, 0, 0);
    pv10 = __builtin_amdgcn_mfma_f32_32x32x16_bf16(pb1.v, bv2, pv10, 0, 0, 0);
    pv11 = __builtin_amdgcn_mfma_f32_32x32x16_bf16(pb1.v, bv3, pv11, 0, 0, 0);
  }

  s2q0 += __shfl_xor(s2q0, 32, 64);
  s2q1 += __shfl_xor(s2q1, 32, 64);
  if (hi == 0) {
    s2slab[w][lp] = s2q0;
    s2slab[w][32 + lp] = s2q1;
  }
#pragma unroll
  for (int reg = 0; reg < 16; reg++) {
    int ql = (reg & 3) + 8 * (reg >> 2) + 4 * hi;
    slab[w][ql][lp] = pv00[reg];
    slab[w][ql][32 + lp] = pv01[reg];
  }
  __syncthreads();
  if (tid < 64) {
    float v = s2slab[0][tid] + s2slab[1][tid] + s2slab[2][tid] + s2slab[3][tid];
    rs2[(size_t)bh * L_ + q0 + tid] = v * (1.0f / 128.0f);
  }
  {
    int q = tid >> 3, seg = tid & 7;
    bf16x8 o;
#pragma unroll
    for (int j = 0; j < 8; j++) {
      int d = seg * 8 + j;
      float acc = slab[0][q][d] + slab[1][q][d] + slab[2][q][d] + slab[3][q][d];
      o[j] = (__bf16)(acc * 0.125f);
    }
    *(bf16x8*)(qkv + ((size_t)bh * L_ + q0 + q) * DH_ + seg * 8) = o;
  }
  __syncthreads();
#pragma unroll
  for (int reg = 0; reg < 16; reg++) {
    int ql = (reg & 3) + 8 * (reg >> 2) + 4 * hi;
    slab[w][ql][lp] = pv10[reg];
    slab[w][ql][32 + lp] = pv11[reg];
  }
  __syncthreads();
  {
    int q = tid >> 3, seg = tid & 7;
    bf16x8 o;
#pragma unroll
    for (int j = 0; j < 8; j++) {
      int d = seg * 8 + j;
      float acc = slab[0][q][d] + slab[1][q][d] + slab[2][q][d] + slab[3][q][d];
      o[j] = (__bf16)(acc * 0.125f);
    }
    *(bf16x8*)(qkv + ((size_t)bh * L_ + q0 + 32 + q) * DH_ + seg * 8) = o;
  }
}

// ---------------- combine (denominator scan fused): Yb += qkv/denom ------
__global__ __launch_bounds__(256)
void combine_kernel(const __bf16* __restrict__ qkv, const float* __restrict__ rs2,
                    __bf16* __restrict__ Yb) {
  int bh = blockIdx.y, lt = blockIdx.x;
  int b = bh / NH_, h = bh % NH_;
  int t = threadIdx.x;
  int l0 = lt * 256;
  __shared__ float part[256];
  __shared__ float dinv[256];
  const float* rs = rs2 + (size_t)bh * L_;
  float vals[8];
  float run = 0.f;
#pragma unroll
  for (int i = 0; i < 8; i++) { run += rs[t * 8 + i]; vals[i] = run; }
  part[t] = run;
  __syncthreads();
  for (int o = 1; o < 256; o <<= 1) {
    float add = (t >= o) ? part[t - o] : 0.f;
    __syncthreads();
    part[t] += add;
    __syncthreads();
  }
  float base = (t > 0) ? part[t - 1] : 0.f;
#pragma unroll
  for (int i = 0; i < 8; i++) {
    int ll = t * 8 + i;
    if (ll >= l0 && ll < l0 + 256)
      dinv[ll - l0] = 1.0f / ((float)(ll + 1) + base + vals[i]);
  }
  __syncthreads();
#pragma unroll
  for (int it = 0; it < 8; it++) {
    int v = it * 256 + t;
    int ll = v >> 3, d8 = v & 7;
    bf16x8 q8 = *(const bf16x8*)(qkv + ((size_t)bh * L_ + l0 + ll) * DH_ + d8 * 8);
    __bf16* yp = Yb + ((size_t)(b * L_ + l0 + ll)) * DM + h * DH_ + d8 * 8;
    bf16x8 y8 = *(const bf16x8*)yp;
    float iv = dinv[ll];
#pragma unroll
    for (int j = 0; j < 8; j++)
      y8[j] = (__bf16)((float)y8[j] + (float)q8[j] * iv);
    *(bf16x8*)yp = y8;
  }
}

extern "C" void kernel_launch(void* const* d_in, const int* in_sizes, int n_in,
                              void* d_out, int out_size, void* d_ws, size_t ws_size,
                              hipStream_t stream) {
  const float* hs = (const float*)d_in[0];
  const float* Wq = (const float*)d_in[1];
  const float* Wk = (const float*)d_in[2];
  const float* Wv = (const float*)d_in[3];
  const float* Wo = (const float*)d_in[4];
  float* out = (float*)d_out;
  char* w = (char*)d_ws;

  __bf16* hsb   = (__bf16*)(w);                      // 6,291,456
  __bf16* WqkvT = (__bf16*)(w + 6291456);            // 1,769,472
  __bf16* WoT   = (__bf16*)(w + 8060928);            // 1,179,648
  __bf16* Kh    = (__bf16*)(w + 9240576);            // 1,572,864
  __bf16* Vh    = (__bf16*)(w + 10813440);           // 6,291,456
  __bf16* qkvb  = (__bf16*)(w + 28114944);           // 6,291,456
  __bf16* Qh    = (__bf16*)(w + 34406400);           // 1,572,864
  __bf16* CKh   = (__bf16*)(w + 35979264);           // 1,572,864
  __bf16* CVfg  = (__bf16*)(w + 37552128);           // 6,291,456
  __bf16* Yb    = (__bf16*)(w + 43843584);           // 6,291,456
  float*  rs2   = (float*)(w + 50135040);            // 98,304
  float*  csum  = (float*)(w + 50331648);            // 245,760

  prep_kernel<<<2976, 256, 0, stream>>>(hs, Wq, Wk, Wv, Wo, hsb, WqkvT, WoT);
  dim3 g1(1152 / 128, (B_ * L_) / 128);
  gemm_bf16<128, 1><<<g1, 256, 0, stream>>>(hsb, WqkvT, B_ * L_, 1152, DM,
                                            nullptr, Qh, Kh, Vh, csum);
  dim3 gs(NCH, B_ * NH_);
  scan_apply<<<gs, 128, 0, stream>>>(Kh, Vh, csum, CKh, CVfg, Yb);
  dim3 g3(L_ / 64, 24);
  attn_mfma<<<g3, 256, 0, stream>>>(Qh, CKh, CVfg, qkvb, rs2);
  dim3 g5(8, 24);
  combine_kernel<<<g5, 256, 0, stream>>>(qkvb, rs2, Yb);
  dim3 g6(DM / 64, (B_ * L_) / 128);
  gemm_bf16<64, 0><<<g6, 256, 0, stream>>>(Yb, WoT, B_ * L_, DM, DM,
                                           out, nullptr, nullptr, nullptr, nullptr);
}

// Round 12
// 108.082 us; speedup vs baseline: 1.6406x; 1.1083x over previous
//
#include <hip/hip_runtime.h>
#include <hip/hip_bf16.h>
#include <stdint.h>

constexpr int B_ = 2, L_ = 2048, DM = 768, NH_ = 12, F_ = 16, DH_ = 64;
constexpr int CH = 32, NCH = L_ / CH;  // scan chunking (32-row chunks)

typedef __bf16 bf16x8 __attribute__((ext_vector_type(8)));
typedef __bf16 bf16x4 __attribute__((ext_vector_type(4)));
typedef float f32x4 __attribute__((ext_vector_type(4)));
typedef float f32x16 __attribute__((ext_vector_type(16)));
typedef unsigned u32x2 __attribute__((ext_vector_type(2)));

#define GLOAD16(g, l)                                                        \
  __builtin_amdgcn_global_load_lds(                                          \
      (const __attribute__((address_space(1))) void*)(g),                    \
      (__attribute__((address_space(3))) void*)(l), 16, 0, 0)

__device__ __forceinline__ unsigned cvt_pk_bf16(float lo, float hi) {
  unsigned r;
  asm("v_cvt_pk_bf16_f32 %0, %1, %2" : "=v"(r) : "v"(lo), "v"(hi));
  return r;
}

union pa_u { unsigned u[4]; bf16x8 v; };

__device__ __forceinline__ void pack_p(const f32x16& s, pa_u& pa0, pa_u& pa1) {
  unsigned w0 = cvt_pk_bf16(s[0], s[1]),   w1 = cvt_pk_bf16(s[2], s[3]);
  unsigned w2 = cvt_pk_bf16(s[4], s[5]),   w3 = cvt_pk_bf16(s[6], s[7]);
  unsigned w4 = cvt_pk_bf16(s[8], s[9]),   w5 = cvt_pk_bf16(s[10], s[11]);
  unsigned w6 = cvt_pk_bf16(s[12], s[13]), w7 = cvt_pk_bf16(s[14], s[15]);
  u32x2 r0 = __builtin_amdgcn_permlane32_swap(w0, w2, false, false);
  u32x2 r1 = __builtin_amdgcn_permlane32_swap(w1, w3, false, false);
  u32x2 r2 = __builtin_amdgcn_permlane32_swap(w4, w6, false, false);
  u32x2 r3 = __builtin_amdgcn_permlane32_swap(w5, w7, false, false);
  pa0.u[0] = r0[0]; pa0.u[1] = r1[0]; pa0.u[2] = r0[1]; pa0.u[3] = r1[1];
  pa1.u[0] = r2[0]; pa1.u[1] = r3[0]; pa1.u[2] = r2[1]; pa1.u[3] = r3[1];
}

// ---------------- prep: LDS-tiled weight transposes + hs cast ------------
__global__ __launch_bounds__(256)
void prep_kernel(const float* __restrict__ hs, const float* __restrict__ Wq,
                 const float* __restrict__ Wk, const float* __restrict__ Wv,
                 const float* __restrict__ Wo, __bf16* __restrict__ hsb,
                 __bf16* __restrict__ WqkvT, __bf16* __restrict__ WoT) {
  int bx = blockIdx.x;
  if (bx < 1440) {
    const float* src; __bf16* dst; int C, kt, nt;
    int id = bx;
    if (id < 144)      { src = Wq; dst = WqkvT;             C = 192; kt = id / 6;  nt = id % 6;  }
    else if (id < 288) { id -= 144; src = Wk; dst = WqkvT + (size_t)192 * 768; C = 192; kt = id / 6;  nt = id % 6;  }
    else if (id < 864) { id -= 288; src = Wv; dst = WqkvT + (size_t)384 * 768; C = 768; kt = id / 24; nt = id % 24; }
    else               { id -= 864; src = Wo; dst = WoT;    C = 768; kt = id / 24; nt = id % 24; }
    __shared__ float ld[32][33];
    int tid = threadIdx.x;
    int r = tid >> 3, cg = tid & 7;
    int k0 = kt * 32, n0 = nt * 32;
    float4 v = *(const float4*)(src + (size_t)(k0 + r) * C + n0 + cg * 4);
    ld[r][cg * 4 + 0] = v.x;
    ld[r][cg * 4 + 1] = v.y;
    ld[r][cg * 4 + 2] = v.z;
    ld[r][cg * 4 + 3] = v.w;
    __syncthreads();
    int nl = tid >> 3, kg = tid & 7;
    bf16x4 o;
#pragma unroll
    for (int j = 0; j < 4; j++) o[j] = (__bf16)ld[kg * 4 + j][nl];
    *(bf16x4*)(dst + (size_t)(n0 + nl) * 768 + k0 + kg * 4) = o;
  } else {
    int base = (bx - 1440) * 2048 + threadIdx.x * 8;
    float4 a = *(const float4*)(hs + base);
    float4 b4 = *(const float4*)(hs + base + 4);
    bf16x8 o;
    o[0] = (__bf16)a.x;  o[1] = (__bf16)a.y;  o[2] = (__bf16)a.z;  o[3] = (__bf16)a.w;
    o[4] = (__bf16)b4.x; o[5] = (__bf16)b4.y; o[6] = (__bf16)b4.z; o[7] = (__bf16)b4.w;
    *(bf16x8*)(hsb + base) = o;
  }
}

// ---------------- bf16 MFMA GEMM (fp32 out), 2-phase double-buffered -----
template<int BN>
__global__ __launch_bounds__(256)
void gemm_bf16(const __bf16* __restrict__ A, const __bf16* __restrict__ Bt,
               int M, int N, int K, float* __restrict__ C) {
  __shared__ __align__(16) __bf16 Al[2][128 * 32];
  __shared__ __align__(16) __bf16 Bl[2][BN * 32];
  int tid = threadIdx.x;
  int m0 = blockIdx.y * 128, n0 = blockIdx.x * BN;
  int w = tid >> 6, l = tid & 63, lr = l & 15, lg = l >> 4;
  constexpr int MI = (BN == 128) ? 4 : 2;
  int rowb = (BN == 128) ? (w >> 1) * 64 : w * 32;
  int colb = (BN == 128) ? (w & 1) * 64 : 0;
  f32x4 acc[MI][4] = {};
  const __bf16* Ab = A + (size_t)m0 * K;
  const __bf16* Bb = Bt + (size_t)n0 * K;
  int nt = K / 32;

  auto stage = [&](int buf, int k0) {
#pragma unroll
    for (int i = 0; i < 2; i++) {
      int idx = i * 256 + tid;
      GLOAD16(Ab + (size_t)(idx >> 2) * K + k0 + (idx & 3) * 8, &Al[buf][idx * 8]);
    }
    if constexpr (BN == 128) {
#pragma unroll
      for (int i = 0; i < 2; i++) {
        int idx = i * 256 + tid;
        GLOAD16(Bb + (size_t)(idx >> 2) * K + k0 + (idx & 3) * 8, &Bl[buf][idx * 8]);
      }
    } else {
      GLOAD16(Bb + (size_t)(tid >> 2) * K + k0 + (tid & 3) * 8, &Bl[buf][tid * 8]);
    }
  };

  stage(0, 0);
  asm volatile("s_waitcnt vmcnt(0)" ::: "memory");
  __syncthreads();
  int cur = 0;
  for (int t = 0; t < nt; t++) {
    if (t + 1 < nt) stage(cur ^ 1, (t + 1) * 32);
    bf16x8 af[MI], bfr[4];
#pragma unroll
    for (int mi = 0; mi < MI; mi++)
      af[mi] = *(const bf16x8*)&Al[cur][(rowb + mi * 16 + lr) * 32 + lg * 8];
#pragma unroll
    for (int ni = 0; ni < 4; ni++)
      bfr[ni] = *(const bf16x8*)&Bl[cur][(colb + ni * 16 + lr) * 32 + lg * 8];
#pragma unroll
    for (int mi = 0; mi < MI; mi++)
#pragma unroll
      for (int ni = 0; ni < 4; ni++)
        acc[mi][ni] = __builtin_amdgcn_mfma_f32_16x16x32_bf16(
            af[mi], bfr[ni], acc[mi][ni], 0, 0, 0);
    asm volatile("s_waitcnt vmcnt(0)" ::: "memory");
    __syncthreads();
    cur ^= 1;
  }

#pragma unroll
  for (int mi = 0; mi < MI; mi++)
#pragma unroll
    for (int ni = 0; ni < 4; ni++) {
      int n = n0 + colb + ni * 16 + lr;
#pragma unroll
      for (int r = 0; r < 4; r++) {
        int m = m0 + rowb + mi * 16 + lg * 4 + r;
        C[(size_t)m * N + n] = acc[mi][ni][r];
      }
    }
}

// ---------------- projection GEMM with Qh/Kh/Vh + csum epilogue ----------
__global__ __launch_bounds__(256)
void gemm_proj(const __bf16* __restrict__ A, const __bf16* __restrict__ Bt,
               int K, __bf16* __restrict__ Qh, __bf16* __restrict__ Kh,
               __bf16* __restrict__ Vh, float* __restrict__ csum) {
  __shared__ __align__(16) __bf16 Al[2][128 * 32];
  __shared__ __align__(16) __bf16 Bl[2][128 * 32];
  __shared__ float csl[4][128];
  int tid = threadIdx.x;
  int m0 = blockIdx.y * 128, n0 = blockIdx.x * 128;
  int w = tid >> 6, l = tid & 63, lr = l & 15, lg = l >> 4;
  int rowb = (w >> 1) * 64, colb = (w & 1) * 64;
  f32x4 acc[4][4] = {};
  const __bf16* Ab = A + (size_t)m0 * K;
  const __bf16* Bb = Bt + (size_t)n0 * K;
  int nt = K / 32;
  auto stage = [&](int buf, int k0) {
#pragma unroll
    for (int i = 0; i < 2; i++) {
      int idx = i * 256 + tid;
      GLOAD16(Ab + (size_t)(idx >> 2) * K + k0 + (idx & 3) * 8, &Al[buf][idx * 8]);
    }
#pragma unroll
    for (int i = 0; i < 2; i++) {
      int idx = i * 256 + tid;
      GLOAD16(Bb + (size_t)(idx >> 2) * K + k0 + (idx & 3) * 8, &Bl[buf][idx * 8]);
    }
  };
  stage(0, 0);
  asm volatile("s_waitcnt vmcnt(0)" ::: "memory");
  __syncthreads();
  int cur = 0;
  for (int t = 0; t < nt; t++) {
    if (t + 1 < nt) stage(cur ^ 1, (t + 1) * 32);
    bf16x8 af[4], bfr[4];
#pragma unroll
    for (int mi = 0; mi < 4; mi++)
      af[mi] = *(const bf16x8*)&Al[cur][(rowb + mi * 16 + lr) * 32 + lg * 8];
#pragma unroll
    for (int ni = 0; ni < 4; ni++)
      bfr[ni] = *(const bf16x8*)&Bl[cur][(colb + ni * 16 + lr) * 32 + lg * 8];
#pragma unroll
    for (int mi = 0; mi < 4; mi++)
#pragma unroll
      for (int ni = 0; ni < 4; ni++)
        acc[mi][ni] = __builtin_amdgcn_mfma_f32_16x16x32_bf16(
            af[mi], bfr[ni], acc[mi][ni], 0, 0, 0);
    asm volatile("s_waitcnt vmcnt(0)" ::: "memory");
    __syncthreads();
    cur ^= 1;
  }
#pragma unroll
  for (int mi = 0; mi < 4; mi++)
#pragma unroll
    for (int ni = 0; ni < 4; ni++) {
      int n = n0 + colb + ni * 16 + lr;
#pragma unroll
      for (int r = 0; r < 4; r++) {
        int m = m0 + rowb + mi * 16 + lg * 4 + r;
        float v = acc[mi][ni][r];
        int b = m >> 11, ll = m & 2047;
        if (n < 192)
          Qh[((size_t)(b * NH_ + (n >> 4)) * L_ + ll) * F_ + (n & 15)] = (__bf16)v;
        else if (n < 384)
          Kh[((size_t)(b * NH_ + ((n - 192) >> 4)) * L_ + ll) * F_ + ((n - 192) & 15)] = (__bf16)v;
        else
          Vh[((size_t)(b * NH_ + ((n - 384) >> 6)) * L_ + ll) * DH_ + ((n - 384) & 63)] = (__bf16)v;
      }
    }
  // per-32-row-chunk column sums (bf16-rounded, self-consistent).
  // wave rows: rowb + mi*16 + lg*4 + r; mi in {0,1} -> rows [rowb, rowb+32),
  // mi in {2,3} -> [rowb+32, rowb+64). Chunk index = (w>>1)*2 + pair.
#pragma unroll
  for (int ni = 0; ni < 4; ni++) {
#pragma unroll
    for (int pair = 0; pair < 2; pair++) {
      float cs = 0.f;
#pragma unroll
      for (int mi = 2 * pair; mi < 2 * pair + 2; mi++)
#pragma unroll
        for (int r = 0; r < 4; r++) cs += (float)(__bf16)acc[mi][ni][r];
      cs += __shfl_xor(cs, 16, 64);
      cs += __shfl_xor(cs, 32, 64);
      if (lg == 0) csl[(w >> 1) * 2 + pair][colb + ni * 16 + lr] = cs;
    }
  }
  __syncthreads();
  for (int i = tid; i < 512; i += 256) {
    int chs = i >> 7, colg = i & 127;
    int n = n0 + colg;
    if (n >= 192) {
      int b = m0 >> 11;
      int ch32 = ((m0 & 2047) >> 5) + chs;
      float v = csl[chs][colg];
      int h, c;
      if (n < 384) { h = (n - 192) >> 4; c = (n - 192) & 15; }
      else         { h = (n - 384) >> 6; c = 16 + ((n - 384) & 63); }
      csum[((size_t)(b * NH_ + h) * NCH + ch32) * 80 + c] = v;
    }
  }
}

// ---------------- apply: prefix base + in-chunk mean scan (bf16 in) ------
__global__ __launch_bounds__(128)
void scan_apply(const __bf16* __restrict__ Kh, const __bf16* __restrict__ Vh,
                const float* __restrict__ csum,
                __bf16* __restrict__ CKh, __bf16* __restrict__ CVf,
                __bf16* __restrict__ Yb) {
  int bh = blockIdx.y, ch = blockIdx.x;
  int b = bh / NH_, h = bh % NH_;
  int c = threadIdx.x;
  if (c >= 80) return;
  float run = 0.f;
  for (int j = 0; j < ch; j++) run += csum[((size_t)bh * NCH + j) * 80 + c];
  if (c < 16) {
    const __bf16* src = Kh + ((size_t)bh * L_ + ch * CH) * F_ + c;
    __bf16* ckp = CKh + ((size_t)bh * L_ + ch * CH) * F_ + c;
    for (int r = 0; r < CH; r++) {
      float val = (float)src[(size_t)r * F_];
      run += val;
      float mean = run * __builtin_amdgcn_rcpf((float)(ch * CH + r + 1));
      ckp[(size_t)r * F_] = (__bf16)(val - mean);
    }
  } else {
    int d = c - 16;
    const __bf16* src = Vh + ((size_t)bh * L_ + ch * CH) * DH_ + d;
    __bf16* cvbase = CVf + (size_t)bh * 128 * 1024;
    __bf16* yp = Yb + ((size_t)(b * L_ + ch * CH)) * DM + h * DH_ + d;
    for (int r = 0; r < CH; r++) {
      float val = (float)src[(size_t)r * DH_];
      run += val;
      int p = ch * CH + r;
      float mean = run * __builtin_amdgcn_rcpf((float)(p + 1));
      cvbase[(size_t)(p >> 4) * 1024 + d * 16 + (p & 15)] = (__bf16)(val - mean);
      yp[(size_t)r * DM] = (__bf16)mean;
    }
  }
}

// ---------------- attention: QBLK=64, KV-split waves, prefetch pipeline --
__global__ __launch_bounds__(256)
void attn_mfma(const __bf16* __restrict__ Qh, const __bf16* __restrict__ CKh,
               const __bf16* __restrict__ CVf, __bf16* __restrict__ qkv,
               float* __restrict__ rs2) {
  __shared__ float slab[4][32][65];
  __shared__ float s2slab[4][64];
  int bh = blockIdx.y;
  int qi = (gridDim.x - 1) - blockIdx.x;  // big tiles first
  int q0 = qi * 64;
  int qt0 = 2 * qi, qt1 = 2 * qi + 1;
  int tid = threadIdx.x;
  int w = tid >> 6, l = tid & 63;
  int lp = l & 31, hi = l >> 5;

  bf16x8 qb0 = *(const bf16x8*)(Qh + ((size_t)bh * L_ + q0 + lp) * F_ + hi * 8);
  bf16x8 qb1 = *(const bf16x8*)(Qh + ((size_t)bh * L_ + q0 + 32 + lp) * F_ + hi * 8);
  const __bf16* ckb = CKh + (size_t)bh * L_ * F_;
  const __bf16* cvb = CVf + (size_t)bh * 128 * 1024;

  f32x16 pv00 = {}, pv01 = {}, pv10 = {}, pv11 = {};
  float s2q0 = 0.f, s2q1 = 0.f;

  // prologue prefetch (clamped-valid index for idle waves)
  int pfirst = (w <= qt1) ? w : 0;
  bf16x8 ka = *(const bf16x8*)(ckb + (size_t)(pfirst * 32 + lp) * F_ + hi * 8);
  const __bf16* cvp = cvb + (size_t)(2 * pfirst) * 1024 + lp * 16 + hi * 8;
  bf16x8 bv0 = *(const bf16x8*)(cvp);
  bf16x8 bv1 = *(const bf16x8*)(cvp + 512);
  bf16x8 bv2 = *(const bf16x8*)(cvp + 1024);
  bf16x8 bv3 = *(const bf16x8*)(cvp + 1536);

  for (int pt = w; pt <= qt1; pt += 4) {
    // prefetch next tile (clamped index -> always valid memory)
    int ptn = (pt + 4 <= qt1) ? pt + 4 : pt;
    bf16x8 ka_n = *(const bf16x8*)(ckb + (size_t)(ptn * 32 + lp) * F_ + hi * 8);
    const __bf16* cvpn = cvb + (size_t)(2 * ptn) * 1024 + lp * 16 + hi * 8;
    bf16x8 bn0 = *(const bf16x8*)(cvpn);
    bf16x8 bn1 = *(const bf16x8*)(cvpn + 512);
    bf16x8 bn2 = *(const bf16x8*)(cvpn + 1024);
    bf16x8 bn3 = *(const bf16x8*)(cvpn + 1536);

    f32x16 s1 = {};
    s1 = __builtin_amdgcn_mfma_f32_32x32x16_bf16(ka, qb1, s1, 0, 0, 0);
    if (pt <= qt0) {
      f32x16 s0 = {};
      s0 = __builtin_amdgcn_mfma_f32_32x32x16_bf16(ka, qb0, s0, 0, 0, 0);
      if (pt == qt0) {
#pragma unroll
        for (int reg = 0; reg < 16; reg++) {
          int pidx = (reg & 3) + 8 * (reg >> 2) + 4 * hi;
          if (pidx > lp) s0[reg] = 0.f;
        }
      }
#pragma unroll
      for (int reg = 0; reg < 16; reg++) s2q0 = fmaf(s0[reg], s0[reg], s2q0);
      pa_u pa0, pa1;
      pack_p(s0, pa0, pa1);
      __builtin_amdgcn_s_setprio(1);
      pv00 = __builtin_amdgcn_mfma_f32_32x32x16_bf16(pa0.v, bv0, pv00, 0, 0, 0);
      pv01 = __builtin_amdgcn_mfma_f32_32x32x16_bf16(pa0.v, bv1, pv01, 0, 0, 0);
      pv00 = __builtin_amdgcn_mfma_f32_32x32x16_bf16(pa1.v, bv2, pv00, 0, 0, 0);
      pv01 = __builtin_amdgcn_mfma_f32_32x32x16_bf16(pa1.v, bv3, pv01, 0, 0, 0);
      __builtin_amdgcn_s_setprio(0);
    }
    if (pt == qt1) {
#pragma unroll
      for (int reg = 0; reg < 16; reg++) {
        int pidx = (reg & 3) + 8 * (reg >> 2) + 4 * hi;
        if (pidx > lp) s1[reg] = 0.f;
      }
    }
#pragma unroll
    for (int reg = 0; reg < 16; reg++) s2q1 = fmaf(s1[reg], s1[reg], s2q1);
    pa_u pb0, pb1;
    pack_p(s1, pb0, pb1);
    __builtin_amdgcn_s_setprio(1);
    pv10 = __builtin_amdgcn_mfma_f32_32x32x16_bf16(pb0.v, bv0, pv10, 0, 0, 0);
    pv11 = __builtin_amdgcn_mfma_f32_32x32x16_bf16(pb0.v, bv1, pv11, 0, 0, 0);
    pv10 = __builtin_amdgcn_mfma_f32_32x32x16_bf16(pb1.v, bv2, pv10, 0, 0, 0);
    pv11 = __builtin_amdgcn_mfma_f32_32x32x16_bf16(pb1.v, bv3, pv11, 0, 0, 0);
    __builtin_amdgcn_s_setprio(0);

    ka = ka_n; bv0 = bn0; bv1 = bn1; bv2 = bn2; bv3 = bn3;
  }

  s2q0 += __shfl_xor(s2q0, 32, 64);
  s2q1 += __shfl_xor(s2q1, 32, 64);
  if (hi == 0) {
    s2slab[w][lp] = s2q0;
    s2slab[w][32 + lp] = s2q1;
  }
#pragma unroll
  for (int reg = 0; reg < 16; reg++) {
    int ql = (reg & 3) + 8 * (reg >> 2) + 4 * hi;
    slab[w][ql][lp] = pv00[reg];
    slab[w][ql][32 + lp] = pv01[reg];
  }
  __syncthreads();
  if (tid < 64) {
    float v = s2slab[0][tid] + s2slab[1][tid] + s2slab[2][tid] + s2slab[3][tid];
    rs2[(size_t)bh * L_ + q0 + tid] = v * (1.0f / 128.0f);
  }
  {
    int q = tid >> 3, seg = tid & 7;
    bf16x8 o;
#pragma unroll
    for (int j = 0; j < 8; j++) {
      int d = seg * 8 + j;
      float acc = slab[0][q][d] + slab[1][q][d] + slab[2][q][d] + slab[3][q][d];
      o[j] = (__bf16)(acc * 0.125f);
    }
    *(bf16x8*)(qkv + ((size_t)bh * L_ + q0 + q) * DH_ + seg * 8) = o;
  }
  __syncthreads();
#pragma unroll
  for (int reg = 0; reg < 16; reg++) {
    int ql = (reg & 3) + 8 * (reg >> 2) + 4 * hi;
    slab[w][ql][lp] = pv10[reg];
    slab[w][ql][32 + lp] = pv11[reg];
  }
  __syncthreads();
  {
    int q = tid >> 3, seg = tid & 7;
    bf16x8 o;
#pragma unroll
    for (int j = 0; j < 8; j++) {
      int d = seg * 8 + j;
      float acc = slab[0][q][d] + slab[1][q][d] + slab[2][q][d] + slab[3][q][d];
      o[j] = (__bf16)(acc * 0.125f);
    }
    *(bf16x8*)(qkv + ((size_t)bh * L_ + q0 + 32 + q) * DH_ + seg * 8) = o;
  }
}

// ---------------- combine (denominator scan fused): Yb += qkv/denom ------
__global__ __launch_bounds__(256)
void combine_kernel(const __bf16* __restrict__ qkv, const float* __restrict__ rs2,
                    __bf16* __restrict__ Yb) {
  int bh = blockIdx.y, lt = blockIdx.x;
  int b = bh / NH_, h = bh % NH_;
  int t = threadIdx.x;
  int l0 = lt * 256;
  __shared__ float part[256];
  __shared__ float dinv[256];
  const float* rs = rs2 + (size_t)bh * L_;
  float vals[8];
  float run = 0.f;
#pragma unroll
  for (int i = 0; i < 8; i++) { run += rs[t * 8 + i]; vals[i] = run; }
  part[t] = run;
  __syncthreads();
  for (int o = 1; o < 256; o <<= 1) {
    float add = (t >= o) ? part[t - o] : 0.f;
    __syncthreads();
    part[t] += add;
    __syncthreads();
  }
  float base = (t > 0) ? part[t - 1] : 0.f;
#pragma unroll
  for (int i = 0; i < 8; i++) {
    int ll = t * 8 + i;
    if (ll >= l0 && ll < l0 + 256)
      dinv[ll - l0] = 1.0f / ((float)(ll + 1) + base + vals[i]);
  }
  __syncthreads();
#pragma unroll
  for (int it = 0; it < 8; it++) {
    int v = it * 256 + t;
    int ll = v >> 3, d8 = v & 7;
    bf16x8 q8 = *(const bf16x8*)(qkv + ((size_t)bh * L_ + l0 + ll) * DH_ + d8 * 8);
    __bf16* yp = Yb + ((size_t)(b * L_ + l0 + ll)) * DM + h * DH_ + d8 * 8;
    bf16x8 y8 = *(const bf16x8*)yp;
    float iv = dinv[ll];
#pragma unroll
    for (int j = 0; j < 8; j++)
      y8[j] = (__bf16)((float)y8[j] + (float)q8[j] * iv);
    *(bf16x8*)yp = y8;
  }
}

extern "C" void kernel_launch(void* const* d_in, const int* in_sizes, int n_in,
                              void* d_out, int out_size, void* d_ws, size_t ws_size,
                              hipStream_t stream) {
  const float* hs = (const float*)d_in[0];
  const float* Wq = (const float*)d_in[1];
  const float* Wk = (const float*)d_in[2];
  const float* Wv = (const float*)d_in[3];
  const float* Wo = (const float*)d_in[4];
  float* out = (float*)d_out;
  char* w = (char*)d_ws;

  __bf16* hsb   = (__bf16*)(w);                      // 6,291,456
  __bf16* WqkvT = (__bf16*)(w + 6291456);            // 1,769,472
  __bf16* WoT   = (__bf16*)(w + 8060928);            // 1,179,648
  __bf16* Kh    = (__bf16*)(w + 9240576);            // 1,572,864
  __bf16* Vh    = (__bf16*)(w + 10813440);           // 6,291,456
  __bf16* qkvb  = (__bf16*)(w + 28114944);           // 6,291,456
  __bf16* Qh    = (__bf16*)(w + 34406400);           // 1,572,864
  __bf16* CKh   = (__bf16*)(w + 35979264);           // 1,572,864
  __bf16* CVfg  = (__bf16*)(w + 37552128);           // 6,291,456
  __bf16* Yb    = (__bf16*)(w + 43843584);           // 6,291,456
  float*  rs2   = (float*)(w + 50135040);            // 98,304
  float*  csum  = (float*)(w + 50331648);            // 491,520

  prep_kernel<<<2976, 256, 0, stream>>>(hs, Wq, Wk, Wv, Wo, hsb, WqkvT, WoT);
  dim3 g1(1152 / 128, (B_ * L_) / 128);
  gemm_proj<<<g1, 256, 0, stream>>>(hsb, WqkvT, DM, Qh, Kh, Vh, csum);
  dim3 gs(NCH, B_ * NH_);
  scan_apply<<<gs, 128, 0, stream>>>(Kh, Vh, csum, CKh, CVfg, Yb);
  dim3 g3(L_ / 64, 24);
  attn_mfma<<<g3, 256, 0, stream>>>(Qh, CKh, CVfg, qkvb, rs2);
  dim3 g5(8, 24);
  combine_kernel<<<g5, 256, 0, stream>>>(qkvb, rs2, Yb);
  dim3 g6(DM / 64, (B_ * L_) / 128);
  gemm_bf16<64><<<g6, 256, 0, stream>>>(Yb, WoT, B_ * L_, DM, DM, out);
}

// Round 14
// 94.951 us; speedup vs baseline: 1.8675x; 1.1383x over previous
//
#include <hip/hip_runtime.h>
#include <hip/hip_bf16.h>
#include <stdint.h>

constexpr int B_ = 2, L_ = 2048, DM = 768, NH_ = 12, F_ = 16, DH_ = 64;
constexpr int CH = 32, NCH = L_ / CH;  // scan chunking (32-row chunks)

typedef __bf16 bf16x8 __attribute__((ext_vector_type(8)));
typedef __bf16 bf16x4 __attribute__((ext_vector_type(4)));
typedef float f32x4 __attribute__((ext_vector_type(4)));
typedef float f32x16 __attribute__((ext_vector_type(16)));
typedef unsigned u32x2 __attribute__((ext_vector_type(2)));

#define GLOAD16(g, l)                                                        \
  __builtin_amdgcn_global_load_lds(                                          \
      (const __attribute__((address_space(1))) void*)(g),                    \
      (__attribute__((address_space(3))) void*)(l), 16, 0, 0)

__device__ __forceinline__ unsigned cvt_pk_bf16(float lo, float hi) {
  unsigned r;
  asm("v_cvt_pk_bf16_f32 %0, %1, %2" : "=v"(r) : "v"(lo), "v"(hi));
  return r;
}

union pa_u { unsigned u[4]; bf16x8 v; };

__device__ __forceinline__ void pack_p(const f32x16& s, pa_u& pa0, pa_u& pa1) {
  unsigned w0 = cvt_pk_bf16(s[0], s[1]),   w1 = cvt_pk_bf16(s[2], s[3]);
  unsigned w2 = cvt_pk_bf16(s[4], s[5]),   w3 = cvt_pk_bf16(s[6], s[7]);
  unsigned w4 = cvt_pk_bf16(s[8], s[9]),   w5 = cvt_pk_bf16(s[10], s[11]);
  unsigned w6 = cvt_pk_bf16(s[12], s[13]), w7 = cvt_pk_bf16(s[14], s[15]);
  u32x2 r0 = __builtin_amdgcn_permlane32_swap(w0, w2, false, false);
  u32x2 r1 = __builtin_amdgcn_permlane32_swap(w1, w3, false, false);
  u32x2 r2 = __builtin_amdgcn_permlane32_swap(w4, w6, false, false);
  u32x2 r3 = __builtin_amdgcn_permlane32_swap(w5, w7, false, false);
  pa0.u[0] = r0[0]; pa0.u[1] = r1[0]; pa0.u[2] = r0[1]; pa0.u[3] = r1[1];
  pa1.u[0] = r2[0]; pa1.u[1] = r3[0]; pa1.u[2] = r2[1]; pa1.u[3] = r3[1];
}

// ---------------- prep: LDS-tiled weight transposes + hs cast ------------
__global__ __launch_bounds__(256)
void prep_kernel(const float* __restrict__ hs, const float* __restrict__ Wq,
                 const float* __restrict__ Wk, const float* __restrict__ Wv,
                 const float* __restrict__ Wo, __bf16* __restrict__ hsb,
                 __bf16* __restrict__ WqkvT, __bf16* __restrict__ WoT) {
  int bx = blockIdx.x;
  if (bx < 1440) {
    const float* src; __bf16* dst; int C, kt, nt;
    int id = bx;
    if (id < 144)      { src = Wq; dst = WqkvT;             C = 192; kt = id / 6;  nt = id % 6;  }
    else if (id < 288) { id -= 144; src = Wk; dst = WqkvT + (size_t)192 * 768; C = 192; kt = id / 6;  nt = id % 6;  }
    else if (id < 864) { id -= 288; src = Wv; dst = WqkvT + (size_t)384 * 768; C = 768; kt = id / 24; nt = id % 24; }
    else               { id -= 864; src = Wo; dst = WoT;    C = 768; kt = id / 24; nt = id % 24; }
    __shared__ float ld[32][33];
    int tid = threadIdx.x;
    int r = tid >> 3, cg = tid & 7;
    int k0 = kt * 32, n0 = nt * 32;
    float4 v = *(const float4*)(src + (size_t)(k0 + r) * C + n0 + cg * 4);
    ld[r][cg * 4 + 0] = v.x;
    ld[r][cg * 4 + 1] = v.y;
    ld[r][cg * 4 + 2] = v.z;
    ld[r][cg * 4 + 3] = v.w;
    __syncthreads();
    int nl = tid >> 3, kg = tid & 7;
    bf16x4 o;
#pragma unroll
    for (int j = 0; j < 4; j++) o[j] = (__bf16)ld[kg * 4 + j][nl];
    *(bf16x4*)(dst + (size_t)(n0 + nl) * 768 + k0 + kg * 4) = o;
  } else {
    int base = (bx - 1440) * 2048 + threadIdx.x * 8;
    float4 a = *(const float4*)(hs + base);
    float4 b4 = *(const float4*)(hs + base + 4);
    bf16x8 o;
    o[0] = (__bf16)a.x;  o[1] = (__bf16)a.y;  o[2] = (__bf16)a.z;  o[3] = (__bf16)a.w;
    o[4] = (__bf16)b4.x; o[5] = (__bf16)b4.y; o[6] = (__bf16)b4.z; o[7] = (__bf16)b4.w;
    *(bf16x8*)(hsb + base) = o;
  }
}

// ---------------- bf16 MFMA GEMM (fp32 out), 2-phase double-buffered -----
template<int BN>
__global__ __launch_bounds__(256)
void gemm_bf16(const __bf16* __restrict__ A, const __bf16* __restrict__ Bt,
               int M, int N, int K, float* __restrict__ C) {
  __shared__ __align__(16) __bf16 Al[2][128 * 32];
  __shared__ __align__(16) __bf16 Bl[2][BN * 32];
  int tid = threadIdx.x;
  int m0 = blockIdx.y * 128, n0 = blockIdx.x * BN;
  int w = tid >> 6, l = tid & 63, lr = l & 15, lg = l >> 4;
  constexpr int MI = (BN == 128) ? 4 : 2;
  int rowb = (BN == 128) ? (w >> 1) * 64 : w * 32;
  int colb = (BN == 128) ? (w & 1) * 64 : 0;
  f32x4 acc[MI][4] = {};
  const __bf16* Ab = A + (size_t)m0 * K;
  const __bf16* Bb = Bt + (size_t)n0 * K;
  int nt = K / 32;

  auto stage = [&](int buf, int k0) {
#pragma unroll
    for (int i = 0; i < 2; i++) {
      int idx = i * 256 + tid;
      GLOAD16(Ab + (size_t)(idx >> 2) * K + k0 + (idx & 3) * 8, &Al[buf][idx * 8]);
    }
    if constexpr (BN == 128) {
#pragma unroll
      for (int i = 0; i < 2; i++) {
        int idx = i * 256 + tid;
        GLOAD16(Bb + (size_t)(idx >> 2) * K + k0 + (idx & 3) * 8, &Bl[buf][idx * 8]);
      }
    } else {
      GLOAD16(Bb + (size_t)(tid >> 2) * K + k0 + (tid & 3) * 8, &Bl[buf][tid * 8]);
    }
  };

  stage(0, 0);
  asm volatile("s_waitcnt vmcnt(0)" ::: "memory");
  __syncthreads();
  int cur = 0;
  for (int t = 0; t < nt; t++) {
    if (t + 1 < nt) stage(cur ^ 1, (t + 1) * 32);
    bf16x8 af[MI], bfr[4];
#pragma unroll
    for (int mi = 0; mi < MI; mi++)
      af[mi] = *(const bf16x8*)&Al[cur][(rowb + mi * 16 + lr) * 32 + lg * 8];
#pragma unroll
    for (int ni = 0; ni < 4; ni++)
      bfr[ni] = *(const bf16x8*)&Bl[cur][(colb + ni * 16 + lr) * 32 + lg * 8];
#pragma unroll
    for (int mi = 0; mi < MI; mi++)
#pragma unroll
      for (int ni = 0; ni < 4; ni++)
        acc[mi][ni] = __builtin_amdgcn_mfma_f32_16x16x32_bf16(
            af[mi], bfr[ni], acc[mi][ni], 0, 0, 0);
    asm volatile("s_waitcnt vmcnt(0)" ::: "memory");
    __syncthreads();
    cur ^= 1;
  }

#pragma unroll
  for (int mi = 0; mi < MI; mi++)
#pragma unroll
    for (int ni = 0; ni < 4; ni++) {
      int n = n0 + colb + ni * 16 + lr;
#pragma unroll
      for (int r = 0; r < 4; r++) {
        int m = m0 + rowb + mi * 16 + lg * 4 + r;
        C[(size_t)m * N + n] = acc[mi][ni][r];
      }
    }
}

// ---------------- projection GEMM (BN=64) with Qh/Kh/Vh + csum -----------
// 128x64 tile, 576 blocks. Wave w owns rows [w*32, w*32+32) = chunk w.
__global__ __launch_bounds__(256)
void gemm_proj(const __bf16* __restrict__ A, const __bf16* __restrict__ Bt,
               int K, __bf16* __restrict__ Qh, __bf16* __restrict__ Kh,
               __bf16* __restrict__ Vh, float* __restrict__ csum) {
  __shared__ __align__(16) __bf16 Al[2][128 * 32];
  __shared__ __align__(16) __bf16 Bl[2][64 * 32];
  __shared__ float csl[4][64];
  int tid = threadIdx.x;
  int m0 = blockIdx.y * 128, n0 = blockIdx.x * 64;
  int w = tid >> 6, l = tid & 63, lr = l & 15, lg = l >> 4;
  int rowb = w * 32;
  f32x4 acc[2][4] = {};
  const __bf16* Ab = A + (size_t)m0 * K;
  const __bf16* Bb = Bt + (size_t)n0 * K;
  int nt = K / 32;
  auto stage = [&](int buf, int k0) {
#pragma unroll
    for (int i = 0; i < 2; i++) {
      int idx = i * 256 + tid;
      GLOAD16(Ab + (size_t)(idx >> 2) * K + k0 + (idx & 3) * 8, &Al[buf][idx * 8]);
    }
    GLOAD16(Bb + (size_t)(tid >> 2) * K + k0 + (tid & 3) * 8, &Bl[buf][tid * 8]);
  };
  stage(0, 0);
  asm volatile("s_waitcnt vmcnt(0)" ::: "memory");
  __syncthreads();
  int cur = 0;
  for (int t = 0; t < nt; t++) {
    if (t + 1 < nt) stage(cur ^ 1, (t + 1) * 32);
    bf16x8 af[2], bfr[4];
#pragma unroll
    for (int mi = 0; mi < 2; mi++)
      af[mi] = *(const bf16x8*)&Al[cur][(rowb + mi * 16 + lr) * 32 + lg * 8];
#pragma unroll
    for (int ni = 0; ni < 4; ni++)
      bfr[ni] = *(const bf16x8*)&Bl[cur][(ni * 16 + lr) * 32 + lg * 8];
#pragma unroll
    for (int mi = 0; mi < 2; mi++)
#pragma unroll
      for (int ni = 0; ni < 4; ni++)
        acc[mi][ni] = __builtin_amdgcn_mfma_f32_16x16x32_bf16(
            af[mi], bfr[ni], acc[mi][ni], 0, 0, 0);
    asm volatile("s_waitcnt vmcnt(0)" ::: "memory");
    __syncthreads();
    cur ^= 1;
  }
#pragma unroll
  for (int mi = 0; mi < 2; mi++)
#pragma unroll
    for (int ni = 0; ni < 4; ni++) {
      int n = n0 + ni * 16 + lr;
#pragma unroll
      for (int r = 0; r < 4; r++) {
        int m = m0 + rowb + mi * 16 + lg * 4 + r;
        float v = acc[mi][ni][r];
        int b = m >> 11, ll = m & 2047;
        if (n < 192)
          Qh[((size_t)(b * NH_ + (n >> 4)) * L_ + ll) * F_ + (n & 15)] = (__bf16)v;
        else if (n < 384)
          Kh[((size_t)(b * NH_ + ((n - 192) >> 4)) * L_ + ll) * F_ + ((n - 192) & 15)] = (__bf16)v;
        else
          Vh[((size_t)(b * NH_ + ((n - 384) >> 6)) * L_ + ll) * DH_ + ((n - 384) & 63)] = (__bf16)v;
      }
    }
  // per-32-row-chunk column sums (wave w = chunk w; bf16-rounded values)
#pragma unroll
  for (int ni = 0; ni < 4; ni++) {
    float cs = 0.f;
#pragma unroll
    for (int mi = 0; mi < 2; mi++)
#pragma unroll
      for (int r = 0; r < 4; r++) cs += (float)(__bf16)acc[mi][ni][r];
    cs += __shfl_xor(cs, 16, 64);
    cs += __shfl_xor(cs, 32, 64);
    if (lg == 0) csl[w][ni * 16 + lr] = cs;
  }
  __syncthreads();
  {
    int chs = tid >> 6, colg = tid & 63;
    int n = n0 + colg;
    if (n >= 192) {
      int b = m0 >> 11;
      int ch32 = ((m0 & 2047) >> 5) + chs;
      float v = csl[chs][colg];
      int h, c;
      if (n < 384) { h = (n - 192) >> 4; c = (n - 192) & 15; }
      else         { h = (n - 384) >> 6; c = 16 + ((n - 384) & 63); }
      csum[((size_t)(b * NH_ + h) * NCH + ch32) * 80 + c] = v;
    }
  }
}

// ---------------- apply: prefix base + in-chunk mean scan (bf16 in) ------
__global__ __launch_bounds__(128)
void scan_apply(const __bf16* __restrict__ Kh, const __bf16* __restrict__ Vh,
                const float* __restrict__ csum,
                __bf16* __restrict__ CKh, __bf16* __restrict__ CVf,
                __bf16* __restrict__ Yb) {
  int bh = blockIdx.y, ch = blockIdx.x;
  int b = bh / NH_, h = bh % NH_;
  int c = threadIdx.x;
  if (c >= 80) return;
  float run = 0.f;
  for (int j = 0; j < ch; j++) run += csum[((size_t)bh * NCH + j) * 80 + c];
  if (c < 16) {
    const __bf16* src = Kh + ((size_t)bh * L_ + ch * CH) * F_ + c;
    __bf16* ckp = CKh + ((size_t)bh * L_ + ch * CH) * F_ + c;
    for (int r = 0; r < CH; r++) {
      float val = (float)src[(size_t)r * F_];
      run += val;
      float mean = run * __builtin_amdgcn_rcpf((float)(ch * CH + r + 1));
      ckp[(size_t)r * F_] = (__bf16)(val - mean);
    }
  } else {
    int d = c - 16;
    const __bf16* src = Vh + ((size_t)bh * L_ + ch * CH) * DH_ + d;
    __bf16* cvbase = CVf + (size_t)bh * 128 * 1024;
    __bf16* yp = Yb + ((size_t)(b * L_ + ch * CH)) * DM + h * DH_ + d;
    for (int r = 0; r < CH; r++) {
      float val = (float)src[(size_t)r * DH_];
      run += val;
      int p = ch * CH + r;
      float mean = run * __builtin_amdgcn_rcpf((float)(p + 1));
      cvbase[(size_t)(p >> 4) * 1024 + d * 16 + (p & 15)] = (__bf16)(val - mean);
      yp[(size_t)r * DM] = (__bf16)mean;
    }
  }
}

// ---------------- attention: paired q-tiles (uniform work), QBLK=32 ------
// block = (bh, pairi); processes q-tile pairi then 63-pairi sequentially.
// Waves split KV (stride 4). In-register P, prefetch pipeline, setprio.
__global__ __launch_bounds__(256)
void attn_mfma(const __bf16* __restrict__ Qh, const __bf16* __restrict__ CKh,
               const __bf16* __restrict__ CVf, __bf16* __restrict__ qkv,
               float* __restrict__ rs2) {
  __shared__ float slab[4][32][65];
  __shared__ float s2slab[4][32];
  int bh = blockIdx.y;
  int pairi = blockIdx.x;
  int tid = threadIdx.x;
  int w = tid >> 6, l = tid & 63;
  int lp = l & 31, hi = l >> 5;
  const __bf16* ckb = CKh + (size_t)bh * L_ * F_;
  const __bf16* cvb = CVf + (size_t)bh * 128 * 1024;

#pragma unroll
  for (int half = 0; half < 2; half++) {
    int ti = half ? (63 - pairi) : pairi;
    int q0 = ti * 32;
    bf16x8 qb = *(const bf16x8*)(Qh + ((size_t)bh * L_ + q0 + lp) * F_ + hi * 8);
    f32x16 pv0 = {}, pv1 = {};
    float s2 = 0.f;

    int pfirst = (w <= ti) ? w : 0;
    bf16x8 ka = *(const bf16x8*)(ckb + (size_t)(pfirst * 32 + lp) * F_ + hi * 8);
    const __bf16* cvp = cvb + (size_t)(2 * pfirst) * 1024 + lp * 16 + hi * 8;
    bf16x8 bv0 = *(const bf16x8*)(cvp);
    bf16x8 bv1 = *(const bf16x8*)(cvp + 512);
    bf16x8 bv2 = *(const bf16x8*)(cvp + 1024);
    bf16x8 bv3 = *(const bf16x8*)(cvp + 1536);

    for (int pt = w; pt <= ti; pt += 4) {
      int ptn = (pt + 4 <= ti) ? pt + 4 : pt;  // clamped prefetch
      bf16x8 ka_n = *(const bf16x8*)(ckb + (size_t)(ptn * 32 + lp) * F_ + hi * 8);
      const __bf16* cvpn = cvb + (size_t)(2 * ptn) * 1024 + lp * 16 + hi * 8;
      bf16x8 bn0 = *(const bf16x8*)(cvpn);
      bf16x8 bn1 = *(const bf16x8*)(cvpn + 512);
      bf16x8 bn2 = *(const bf16x8*)(cvpn + 1024);
      bf16x8 bn3 = *(const bf16x8*)(cvpn + 1536);

      f32x16 s = {};
      s = __builtin_amdgcn_mfma_f32_32x32x16_bf16(ka, qb, s, 0, 0, 0);
      if (pt == ti) {
#pragma unroll
        for (int reg = 0; reg < 16; reg++) {
          int pidx = (reg & 3) + 8 * (reg >> 2) + 4 * hi;
          if (pidx > lp) s[reg] = 0.f;
        }
      }
#pragma unroll
      for (int reg = 0; reg < 16; reg++) s2 = fmaf(s[reg], s[reg], s2);
      pa_u pa0, pa1;
      pack_p(s, pa0, pa1);
      __builtin_amdgcn_s_setprio(1);
      pv0 = __builtin_amdgcn_mfma_f32_32x32x16_bf16(pa0.v, bv0, pv0, 0, 0, 0);
      pv1 = __builtin_amdgcn_mfma_f32_32x32x16_bf16(pa0.v, bv1, pv1, 0, 0, 0);
      pv0 = __builtin_amdgcn_mfma_f32_32x32x16_bf16(pa1.v, bv2, pv0, 0, 0, 0);
      pv1 = __builtin_amdgcn_mfma_f32_32x32x16_bf16(pa1.v, bv3, pv1, 0, 0, 0);
      __builtin_amdgcn_s_setprio(0);
      ka = ka_n; bv0 = bn0; bv1 = bn1; bv2 = bn2; bv3 = bn3;
    }

    s2 += __shfl_xor(s2, 32, 64);
    if (hi == 0) s2slab[w][lp] = s2;
#pragma unroll
    for (int reg = 0; reg < 16; reg++) {
      int ql = (reg & 3) + 8 * (reg >> 2) + 4 * hi;
      slab[w][ql][lp] = pv0[reg];
      slab[w][ql][32 + lp] = pv1[reg];
    }
    __syncthreads();
    if (tid < 32) {
      float v = s2slab[0][tid] + s2slab[1][tid] + s2slab[2][tid] + s2slab[3][tid];
      rs2[(size_t)bh * L_ + q0 + tid] = v * (1.0f / 128.0f);
    }
    {
      int q = tid >> 3, seg = tid & 7;
      bf16x8 o;
#pragma unroll
      for (int j = 0; j < 8; j++) {
        int d = seg * 8 + j;
        float acc = slab[0][q][d] + slab[1][q][d] + slab[2][q][d] + slab[3][q][d];
        o[j] = (__bf16)(acc * 0.125f);
      }
      *(bf16x8*)(qkv + ((size_t)bh * L_ + q0 + q) * DH_ + seg * 8) = o;
    }
    if (half == 0) __syncthreads();  // slab reuse hazard
  }
}

// ---------------- combine (denominator scan fused): Yb += qkv/denom ------
__global__ __launch_bounds__(256)
void combine_kernel(const __bf16* __restrict__ qkv, const float* __restrict__ rs2,
                    __bf16* __restrict__ Yb) {
  int bh = blockIdx.y, lt = blockIdx.x;
  int b = bh / NH_, h = bh % NH_;
  int t = threadIdx.x;
  int l0 = lt * 256;
  __shared__ float part[256];
  __shared__ float dinv[256];
  const float* rs = rs2 + (size_t)bh * L_;
  float vals[8];
  float run = 0.f;
#pragma unroll
  for (int i = 0; i < 8; i++) { run += rs[t * 8 + i]; vals[i] = run; }
  part[t] = run;
  __syncthreads();
  for (int o = 1; o < 256; o <<= 1) {
    float add = (t >= o) ? part[t - o] : 0.f;
    __syncthreads();
    part[t] += add;
    __syncthreads();
  }
  float base = (t > 0) ? part[t - 1] : 0.f;
#pragma unroll
  for (int i = 0; i < 8; i++) {
    int ll = t * 8 + i;
    if (ll >= l0 && ll < l0 + 256)
      dinv[ll - l0] = 1.0f / ((float)(ll + 1) + base + vals[i]);
  }
  __syncthreads();
#pragma unroll
  for (int it = 0; it < 8; it++) {
    int v = it * 256 + t;
    int ll = v >> 3, d8 = v & 7;
    bf16x8 q8 = *(const bf16x8*)(qkv + ((size_t)bh * L_ + l0 + ll) * DH_ + d8 * 8);
    __bf16* yp = Yb + ((size_t)(b * L_ + l0 + ll)) * DM + h * DH_ + d8 * 8;
    bf16x8 y8 = *(const bf16x8*)yp;
    float iv = dinv[ll];
#pragma unroll
    for (int j = 0; j < 8; j++)
      y8[j] = (__bf16)((float)y8[j] + (float)q8[j] * iv);
    *(bf16x8*)yp = y8;
  }
}

extern "C" void kernel_launch(void* const* d_in, const int* in_sizes, int n_in,
                              void* d_out, int out_size, void* d_ws, size_t ws_size,
                              hipStream_t stream) {
  const float* hs = (const float*)d_in[0];
  const float* Wq = (const float*)d_in[1];
  const float* Wk = (const float*)d_in[2];
  const float* Wv = (const float*)d_in[3];
  const float* Wo = (const float*)d_in[4];
  float* out = (float*)d_out;
  char* w = (char*)d_ws;

  __bf16* hsb   = (__bf16*)(w);                      // 6,291,456
  __bf16* WqkvT = (__bf16*)(w + 6291456);            // 1,769,472
  __bf16* WoT   = (__bf16*)(w + 8060928);            // 1,179,648
  __bf16* Kh    = (__bf16*)(w + 9240576);            // 1,572,864
  __bf16* Vh    = (__bf16*)(w + 10813440);           // 6,291,456
  __bf16* qkvb  = (__bf16*)(w + 28114944);           // 6,291,456
  __bf16* Qh    = (__bf16*)(w + 34406400);           // 1,572,864
  __bf16* CKh   = (__bf16*)(w + 35979264);           // 1,572,864
  __bf16* CVfg  = (__bf16*)(w + 37552128);           // 6,291,456
  __bf16* Yb    = (__bf16*)(w + 43843584);           // 6,291,456
  float*  rs2   = (float*)(w + 50135040);            // 98,304
  float*  csum  = (float*)(w + 50331648);            // 491,520

  prep_kernel<<<2976, 256, 0, stream>>>(hs, Wq, Wk, Wv, Wo, hsb, WqkvT, WoT);
  dim3 g1(1152 / 64, (B_ * L_) / 128);
  gemm_proj<<<g1, 256, 0, stream>>>(hsb, WqkvT, DM, Qh, Kh, Vh, csum);
  dim3 gs(NCH, B_ * NH_);
  scan_apply<<<gs, 128, 0, stream>>>(Kh, Vh, csum, CKh, CVfg, Yb);
  dim3 g3(32, 24);
  attn_mfma<<<g3, 256, 0, stream>>>(Qh, CKh, CVfg, qkvb, rs2);
  dim3 g5(8, 24);
  combine_kernel<<<g5, 256, 0, stream>>>(qkvb, rs2, Yb);
  dim3 g6(DM / 64, (B_ * L_) / 128);
  gemm_bf16<64><<<g6, 256, 0, stream>>>(Yb, WoT, B_ * L_, DM, DM, out);
}